// Round 1
// baseline (9774.915 us; speedup 1.0000x reference)
//
#include <hip/hip_runtime.h>
#include <cmath>

// Problem constants
#define DIMC   1024
#define SEQC   512
#define BC     4
#define MC     2048      // MAXMEM
#define CTXC   2560      // MC + SEQC
#define HEADSC 16
#define DHC    64
#define VOCABC 32000

// ---------------- embed: x[b,i,:] = token_emb[tokens[b,i],:] ----------------
__global__ __launch_bounds__(256) void embed_kernel(const int* __restrict__ tokens,
                                                    const float* __restrict__ emb,
                                                    float* __restrict__ x) {
    int row = blockIdx.x;                 // b*SEQ + i, 0..2047
    int tok = tokens[row];
    const float4 v = *(const float4*)(emb + (size_t)tok * DIMC + threadIdx.x * 4);
    *(float4*)(x + (size_t)row * DIMC + threadIdx.x * 4) = v;
}

// ---------------- new_times + aux zero ----------------
__global__ __launch_bounds__(256) void times_init_kernel(const int* __restrict__ times,
                                                         float* __restrict__ out_times,
                                                         float* __restrict__ aux) {
    int i = blockIdx.x * 256 + threadIdx.x;
    if (i == 0) aux[0] = 0.0f;
    if (i < 4 * MC) {
        int d = i >> 11, m = i & (MC - 1);
        out_times[i] = (m < MC - SEQC) ? (float)(times[d * MC + SEQC + m] + SEQC)
                                       : (float)(MC - 1 - m);
    }
}

// ---------------- new_mems for one layer: concat(mem, hidden)[:, -M:] ----------------
__global__ __launch_bounds__(256) void newmem_kernel(const float* __restrict__ mem_d,
                                                     const float* __restrict__ x,
                                                     float* __restrict__ out) {
    size_t i = (size_t)blockIdx.x * 256 + threadIdx.x;  // float4 index, total B*M*256
    int c4 = (int)(i & 255);
    size_t rowi = i >> 8;                 // b*M + m
    int m = (int)(rowi & (MC - 1));
    int b = (int)(rowi >> 11);
    const float* src = (m < MC - SEQC)
        ? mem_d + ((size_t)(b * MC + m + SEQC)) * DIMC
        : x + ((size_t)(b * SEQC + m - (MC - SEQC))) * DIMC;
    *(float4*)(out + rowi * DIMC + c4 * 4) = *(const float4*)(src + c4 * 4);
}

// ---------------- expire span: exps = sigmoid(mem·W + b)*M, aux += sum(exps)*COEF/SEQ ----------------
__global__ __launch_bounds__(256) void expire_kernel(const float* __restrict__ mem_d,
                                                     const float* __restrict__ eW,
                                                     const float* __restrict__ eb,
                                                     float* __restrict__ exps,
                                                     float* __restrict__ aux) {
    int row = blockIdx.x;                 // b*M + m
    int tid = threadIdx.x;
    const float4 v = *(const float4*)(mem_d + (size_t)row * DIMC + tid * 4);
    const float4 w = *(const float4*)(eW + tid * 4);
    float s = v.x * w.x + v.y * w.y + v.z * w.z + v.w * w.w;
    for (int off = 32; off; off >>= 1) s += __shfl_down(s, off, 64);
    __shared__ float ss[4];
    int wid = tid >> 6, lane = tid & 63;
    if (lane == 0) ss[wid] = s;
    __syncthreads();
    if (tid == 0) {
        float z = ss[0] + ss[1] + ss[2] + ss[3] + eb[0];
        float e = (float)MC / (1.0f + expf(-z));
        exps[row] = e;
        atomicAdd(aux, e * (1e-6f / (float)SEQC));
    }
}

// ---------------- LayerNorm over last dim (1024), one block per row ----------------
__global__ __launch_bounds__(256) void ln_kernel(const float* __restrict__ in,
                                                 const float* __restrict__ g,
                                                 const float* __restrict__ b,
                                                 float* __restrict__ out) {
    int row = blockIdx.x;
    int tid = threadIdx.x;
    const float4 v = *(const float4*)(in + (size_t)row * DIMC + tid * 4);
    float s = v.x + v.y + v.z + v.w;
    float q = v.x * v.x + v.y * v.y + v.z * v.z + v.w * v.w;
    for (int off = 32; off; off >>= 1) {
        s += __shfl_down(s, off, 64);
        q += __shfl_down(q, off, 64);
    }
    __shared__ float ss[4], sq[4];
    int wid = tid >> 6, lane = tid & 63;
    if (lane == 0) { ss[wid] = s; sq[wid] = q; }
    __syncthreads();
    if (tid == 0) {
        float S = ss[0] + ss[1] + ss[2] + ss[3];
        float Q = sq[0] + sq[1] + sq[2] + sq[3];
        float mu = S / DIMC;
        float var = Q / DIMC - mu * mu;
        ss[0] = mu;
        sq[0] = rsqrtf(var + 1e-5f);
    }
    __syncthreads();
    float mu = ss[0], rstd = sq[0];
    const float4 gg = *(const float4*)(g + tid * 4);
    const float4 bb = *(const float4*)(b + tid * 4);
    float4 o;
    o.x = (v.x - mu) * rstd * gg.x + bb.x;
    o.y = (v.y - mu) * rstd * gg.y + bb.y;
    o.z = (v.z - mu) * rstd * gg.z + bb.z;
    o.w = (v.w - mu) * rstd * gg.w + bb.w;
    *(float4*)(out + (size_t)row * DIMC + tid * 4) = o;
}

// ---------------- fp32 GEMM: C = act(A@W + bias) + res ----------------
// 128x128 tile, BK=16, 256 threads, 8x8 micro-tile.
// GATHER: A rows come from concat(mem(2048 rows/b), xn(512 rows/b)) per batch.
template<bool GATHER, bool BIAS, bool GELU, bool RES>
__global__ __launch_bounds__(256) void gemm_kernel(
    const float* __restrict__ A, const float* __restrict__ A2,
    const float* __restrict__ W, const float* __restrict__ bias,
    const float* __restrict__ res, float* __restrict__ C,
    int rows, int K, int N) {
    __shared__ float As[16][128];
    __shared__ float Ws[16][128];
    int tid = threadIdx.x;
    int col0 = blockIdx.x * 128, row0 = blockIdx.y * 128;
    int tx = tid & 15, ty = tid >> 4;
    int arow = tid >> 1, ak = (tid & 1) * 8;
    int wk = tid >> 4, wn = (tid & 15) * 8;

    const float* arp;
    {
        int r = row0 + arow;
        if (GATHER) {
            int b = r / CTXC, rr = r - b * CTXC;
            arp = (rr < MC) ? A + ((size_t)(b * MC + rr)) * K
                            : A2 + ((size_t)(b * SEQC + rr - MC)) * K;
        } else {
            arp = A + (size_t)r * K;
        }
    }

    float acc[8][8];
    #pragma unroll
    for (int i = 0; i < 8; ++i)
        #pragma unroll
        for (int j = 0; j < 8; ++j) acc[i][j] = 0.0f;

    float4 a0 = *(const float4*)(arp + ak);
    float4 a1 = *(const float4*)(arp + ak + 4);
    float4 w0 = *(const float4*)(W + (size_t)wk * N + col0 + wn);
    float4 w1 = *(const float4*)(W + (size_t)wk * N + col0 + wn + 4);

    for (int k0 = 0;;) {
        __syncthreads();
        As[ak + 0][arow] = a0.x; As[ak + 1][arow] = a0.y;
        As[ak + 2][arow] = a0.z; As[ak + 3][arow] = a0.w;
        As[ak + 4][arow] = a1.x; As[ak + 5][arow] = a1.y;
        As[ak + 6][arow] = a1.z; As[ak + 7][arow] = a1.w;
        *(float4*)&Ws[wk][wn] = w0;
        *(float4*)&Ws[wk][wn + 4] = w1;
        __syncthreads();
        k0 += 16;
        if (k0 < K) {
            a0 = *(const float4*)(arp + k0 + ak);
            a1 = *(const float4*)(arp + k0 + ak + 4);
            w0 = *(const float4*)(W + (size_t)(k0 + wk) * N + col0 + wn);
            w1 = *(const float4*)(W + (size_t)(k0 + wk) * N + col0 + wn + 4);
        }
        #pragma unroll
        for (int kk = 0; kk < 16; ++kk) {
            float4 av0 = *(const float4*)&As[kk][ty * 8];
            float4 av1 = *(const float4*)&As[kk][ty * 8 + 4];
            float4 bv0 = *(const float4*)&Ws[kk][tx * 8];
            float4 bv1 = *(const float4*)&Ws[kk][tx * 8 + 4];
            float ar[8] = {av0.x, av0.y, av0.z, av0.w, av1.x, av1.y, av1.z, av1.w};
            float br[8] = {bv0.x, bv0.y, bv0.z, bv0.w, bv1.x, bv1.y, bv1.z, bv1.w};
            #pragma unroll
            for (int i = 0; i < 8; ++i)
                #pragma unroll
                for (int j = 0; j < 8; ++j)
                    acc[i][j] += ar[i] * br[j];
        }
        if (k0 >= K) break;
    }

    #pragma unroll
    for (int i = 0; i < 8; ++i) {
        size_t r = row0 + ty * 8 + i;
        float* cp = C + r * N + col0 + tx * 8;
        float vout[8];
        #pragma unroll
        for (int j = 0; j < 8; ++j) {
            float v = acc[i][j];
            if (BIAS) v += bias[col0 + tx * 8 + j];
            if (GELU) v = 0.5f * v * (1.0f + erff(v * 0.70710678118f));
            vout[j] = v;
        }
        if (RES) {
            const float* rp = res + r * N + col0 + tx * 8;
            float4 r0 = *(const float4*)rp, r1 = *(const float4*)(rp + 4);
            vout[0] += r0.x; vout[1] += r0.y; vout[2] += r0.z; vout[3] += r0.w;
            vout[4] += r1.x; vout[5] += r1.y; vout[6] += r1.z; vout[7] += r1.w;
        }
        float4 o0 = {vout[0], vout[1], vout[2], vout[3]};
        float4 o1 = {vout[4], vout[5], vout[6], vout[7]};
        *(float4*)cp = o0;
        *(float4*)(cp + 4) = o1;
    }
}

// ---------------- flash attention with expire mask ----------------
// block = 256 threads handles (b, h, 32 queries). Keys tiled by 64.
// attn = softmax(QK^T*scale, causal j<=i+M) * emask;  out = attn @ V
// online softmax: l excludes emask (softmax normalized first, then masked)
__global__ __launch_bounds__(256) void attn_kernel(
    const float* __restrict__ q, const float* __restrict__ kv,
    const float* __restrict__ exps, const int* __restrict__ times_d,
    float* __restrict__ out) {
    __shared__ float k_s[64][68];
    __shared__ float v_s[64][68];
    __shared__ float p_s[32][68];   // doubles as q staging
    __shared__ float em_s[64];
    int tid = threadIdx.x;
    int qt = blockIdx.x;            // 0..15
    int h = blockIdx.y;             // 0..15
    int b = blockIdx.z;             // 0..3
    int qloc = tid >> 3, sub = tid & 7;
    int gq = qt * 32 + qloc;

    // stage Q tile into p_s (coalesced), then pull own row into regs
    {
        int r = tid >> 3;
        int c = (tid & 7) * 8;
        const float* qp = q + ((size_t)(b * SEQC + qt * 32 + r)) * DIMC + h * DHC + c;
        *(float4*)&p_s[r][c] = *(const float4*)qp;
        *(float4*)&p_s[r][c + 4] = *(const float4*)(qp + 4);
    }
    __syncthreads();
    float4 qv[16];
    #pragma unroll
    for (int i = 0; i < 16; ++i) qv[i] = *(const float4*)&p_s[qloc][i * 4];

    float m = -1e30f, l = 0.0f;
    float acc[8] = {0, 0, 0, 0, 0, 0, 0, 0};
    int nkt = (MC + qt * 32 + 31) / 64 + 1;
    const float* kvb = kv + (size_t)b * CTXC * (2 * DIMC);

    for (int kt = 0; kt < nkt; ++kt) {
        int jbase = kt * 64;
        __syncthreads();   // protect LDS from previous iteration / q staging reads
        #pragma unroll
        for (int it = 0; it < 4; ++it) {
            int f = it * 256 + tid;
            int j = f >> 4, c = (f & 15) * 4;
            const float* src = kvb + (size_t)(jbase + j) * (2 * DIMC) + h * DHC + c;
            *(float4*)&k_s[j][c] = *(const float4*)src;
            *(float4*)&v_s[j][c] = *(const float4*)(src + DIMC);
        }
        if (tid < 64) {
            int jg = jbase + tid;
            float em = 1.0f;
            if (jg < MC) {
                float rr = (exps[b * MC + jg] - (float)times_d[jg]) * (1.0f / 128.0f) + 1.0f;
                em = fminf(fmaxf(rr, 0.0f), 1.0f);
            }
            em_s[tid] = em;
        }
        __syncthreads();

        // dots for this thread's 8 keys (strided: jloc = it*8 + sub)
        float p[8];
        float mx = -1e30f;
        #pragma unroll
        for (int it = 0; it < 8; ++it) {
            int jloc = it * 8 + sub;
            int jg = jbase + jloc;
            float4 d4 = {0, 0, 0, 0};
            #pragma unroll
            for (int i = 0; i < 16; ++i) {
                float4 kk4 = *(const float4*)&k_s[jloc][i * 4];
                d4.x += qv[i].x * kk4.x;
                d4.y += qv[i].y * kk4.y;
                d4.z += qv[i].z * kk4.z;
                d4.w += qv[i].w * kk4.w;
            }
            float s = (d4.x + d4.y + d4.z + d4.w) * 0.125f;
            s = (jg <= gq + MC) ? s : -1e30f;
            p[it] = s;
            mx = fmaxf(mx, s);
        }
        mx = fmaxf(mx, __shfl_xor(mx, 1, 64));
        mx = fmaxf(mx, __shfl_xor(mx, 2, 64));
        mx = fmaxf(mx, __shfl_xor(mx, 4, 64));
        float mnew = fmaxf(m, mx);
        float f = expf(m - mnew);
        float psum = 0.0f;
        #pragma unroll
        for (int it = 0; it < 8; ++it) {
            float pe = expf(p[it] - mnew);
            p[it] = pe;
            psum += pe;
        }
        psum += __shfl_xor(psum, 1, 64);
        psum += __shfl_xor(psum, 2, 64);
        psum += __shfl_xor(psum, 4, 64);
        l = l * f + psum;
        #pragma unroll
        for (int i = 0; i < 8; ++i) acc[i] *= f;
        m = mnew;
        #pragma unroll
        for (int it = 0; it < 8; ++it) {
            int jloc = it * 8 + sub;
            p_s[qloc][jloc] = p[it] * em_s[jloc];
        }
        __syncthreads();
        // AV: acc[d] += sum_j p[j] * v[j][d], this thread owns dims sub*8..+7
        #pragma unroll
        for (int j = 0; j < 64; ++j) {
            float pv = p_s[qloc][j];
            float4 v0 = *(const float4*)&v_s[j][sub * 8];
            float4 v1 = *(const float4*)&v_s[j][sub * 8 + 4];
            acc[0] += pv * v0.x; acc[1] += pv * v0.y;
            acc[2] += pv * v0.z; acc[3] += pv * v0.w;
            acc[4] += pv * v1.x; acc[5] += pv * v1.y;
            acc[6] += pv * v1.z; acc[7] += pv * v1.w;
        }
    }
    float inv = 1.0f / l;
    float4 o0 = {acc[0] * inv, acc[1] * inv, acc[2] * inv, acc[3] * inv};
    float4 o1 = {acc[4] * inv, acc[5] * inv, acc[6] * inv, acc[7] * inv};
    float* op = out + ((size_t)(b * SEQC + gq)) * DIMC + h * DHC + sub * 8;
    *(float4*)op = o0;
    *(float4*)(op + 4) = o1;
}

// ---------------- aux writeback ----------------
__global__ void aux_write_kernel(const float* __restrict__ aux, float* __restrict__ dst) {
    dst[0] = aux[0];
}

extern "C" void kernel_launch(void* const* d_in, const int* in_sizes, int n_in,
                              void* d_out, int out_size, void* d_ws, size_t ws_size,
                              hipStream_t stream) {
    const int*   tokens    = (const int*)d_in[0];
    const float* mems      = (const float*)d_in[1];
    const int*   times     = (const int*)d_in[2];
    const float* token_emb = (const float*)d_in[3];
    const float* expire_W  = (const float*)d_in[4];
    const float* expire_b  = (const float*)d_in[5];
    const float* ln1_g     = (const float*)d_in[6];
    const float* ln1_b     = (const float*)d_in[7];
    const float* Wq        = (const float*)d_in[8];
    const float* Wkv       = (const float*)d_in[9];
    const float* Wo        = (const float*)d_in[10];
    const float* bo        = (const float*)d_in[11];
    const float* ln2_g     = (const float*)d_in[12];
    const float* ln2_b     = (const float*)d_in[13];
    const float* W1        = (const float*)d_in[14];
    const float* b1        = (const float*)d_in[15];
    const float* W2        = (const float*)d_in[16];
    const float* b2        = (const float*)d_in[17];
    const float* logits_W  = (const float*)d_in[18];
    const float* logits_b  = (const float*)d_in[19];

    float* out = (float*)d_out;
    float* ws  = (float*)d_ws;

    // workspace layout (floats)
    float* x    = ws;                  // 2,097,152
    float* xn   = ws + 2097152;        // 2,097,152
    float* qb   = ws + 4194304;        // 2,097,152
    float* attn = ws + 6291456;        // 2,097,152
    float* exps = ws + 8388608;        // 8,192
    float* aux  = ws + 8396800;        // 16
    float* kvb  = ws + 8396816;        // 20,971,520
    float* ffn  = kvb;                 // alias (kv dead after attention)

    float* out_logits = out;                // 65,536,000
    float* out_mems   = out + 65536000;     // 33,554,432
    float* out_times  = out + 99090432;     // 8,192
    // aux scalar at out[99098624]

    embed_kernel<<<BC * SEQC, 256, 0, stream>>>(tokens, token_emb, x);
    times_init_kernel<<<32, 256, 0, stream>>>(times, out_times, aux);

    for (int d = 0; d < 4; ++d) {
        const float* mem_d = mems + (size_t)d * BC * MC * DIMC;
        newmem_kernel<<<8192, 256, 0, stream>>>(mem_d, x, out_mems + (size_t)d * BC * MC * DIMC);
        expire_kernel<<<BC * MC, 256, 0, stream>>>(mem_d, expire_W + d * DIMC, expire_b + d, exps, aux);
        ln_kernel<<<BC * SEQC, 256, 0, stream>>>(x, ln1_g + d * DIMC, ln1_b + d * DIMC, xn);
        gemm_kernel<false, false, false, false><<<dim3(8, 16), 256, 0, stream>>>(
            xn, nullptr, Wq + (size_t)d * DIMC * DIMC, nullptr, nullptr, qb,
            BC * SEQC, DIMC, DIMC);
        gemm_kernel<true, false, false, false><<<dim3(16, 80), 256, 0, stream>>>(
            mem_d, xn, Wkv + (size_t)d * DIMC * 2 * DIMC, nullptr, nullptr, kvb,
            BC * CTXC, DIMC, 2 * DIMC);
        attn_kernel<<<dim3(16, HEADSC, BC), 256, 0, stream>>>(qb, kvb, exps, times + d * MC, attn);
        gemm_kernel<false, true, false, true><<<dim3(8, 16), 256, 0, stream>>>(
            attn, nullptr, Wo + (size_t)d * DIMC * DIMC, bo + d * DIMC, x, x,
            BC * SEQC, DIMC, DIMC);
        ln_kernel<<<BC * SEQC, 256, 0, stream>>>(x, ln2_g + d * DIMC, ln2_b + d * DIMC, xn);
        gemm_kernel<false, true, true, false><<<dim3(32, 16), 256, 0, stream>>>(
            xn, nullptr, W1 + (size_t)d * DIMC * 4 * DIMC, b1 + d * 4 * DIMC, nullptr, ffn,
            BC * SEQC, DIMC, 4 * DIMC);
        gemm_kernel<false, true, false, true><<<dim3(8, 16), 256, 0, stream>>>(
            ffn, nullptr, W2 + (size_t)d * 4 * DIMC * DIMC, b2 + d * DIMC, x, x,
            BC * SEQC, 4 * DIMC, DIMC);
    }

    gemm_kernel<false, true, false, false><<<dim3(250, 16), 256, 0, stream>>>(
        x, nullptr, logits_W, logits_b, nullptr, out_logits,
        BC * SEQC, DIMC, VOCABC);
    aux_write_kernel<<<1, 1, 0, stream>>>(aux, out + 99098624);
}

// Round 2
// 3763.945 us; speedup vs baseline: 2.5970x; 2.5970x over previous
//
#include <hip/hip_runtime.h>
#include <cmath>

// Problem constants
#define DIMC   1024
#define SEQC   512
#define BC     4
#define MC     2048      // MAXMEM
#define CTXC   2560      // MC + SEQC
#define HEADSC 16
#define DHC    64
#define VOCABC 32000

using short8 = __attribute__((ext_vector_type(8))) short;
using f32x4  = __attribute__((ext_vector_type(4))) float;
using u16x4  = __attribute__((ext_vector_type(4))) unsigned short;
using u16x8  = __attribute__((ext_vector_type(8))) unsigned short;

__device__ __forceinline__ unsigned short f2bf(float f) {
    unsigned u = __float_as_uint(f);
    unsigned r = (u + 0x7fffu + ((u >> 16) & 1u)) >> 16;
    return (unsigned short)r;
}

__device__ __forceinline__ void glds16(const unsigned short* g, char* l) {
    __builtin_amdgcn_global_load_lds(
        (const __attribute__((address_space(1))) void*)g,
        (__attribute__((address_space(3))) void*)l, 16, 0, 0);
}

// ---------------- embed ----------------
__global__ __launch_bounds__(256) void embed_kernel(const int* __restrict__ tokens,
                                                    const float* __restrict__ emb,
                                                    float* __restrict__ x) {
    int row = blockIdx.x;
    int tok = tokens[row];
    const float4 v = *(const float4*)(emb + (size_t)tok * DIMC + threadIdx.x * 4);
    *(float4*)(x + (size_t)row * DIMC + threadIdx.x * 4) = v;
}

// ---------------- new_times + aux zero ----------------
__global__ __launch_bounds__(256) void times_init_kernel(const int* __restrict__ times,
                                                         float* __restrict__ out_times,
                                                         float* __restrict__ aux) {
    int i = blockIdx.x * 256 + threadIdx.x;
    if (i == 0) aux[0] = 0.0f;
    if (i < 4 * MC) {
        int d = i >> 11, m = i & (MC - 1);
        out_times[i] = (m < MC - SEQC) ? (float)(times[d * MC + SEQC + m] + SEQC)
                                       : (float)(MC - 1 - m);
    }
}

// ---------------- new_mems ----------------
__global__ __launch_bounds__(256) void newmem_kernel(const float* __restrict__ mem_d,
                                                     const float* __restrict__ x,
                                                     float* __restrict__ out) {
    size_t i = (size_t)blockIdx.x * 256 + threadIdx.x;
    int c4 = (int)(i & 255);
    size_t rowi = i >> 8;
    int m = (int)(rowi & (MC - 1));
    int b = (int)(rowi >> 11);
    const float* src = (m < MC - SEQC)
        ? mem_d + ((size_t)(b * MC + m + SEQC)) * DIMC
        : x + ((size_t)(b * SEQC + m - (MC - SEQC))) * DIMC;
    *(float4*)(out + rowi * DIMC + c4 * 4) = *(const float4*)(src + c4 * 4);
}

// ---------------- expire span ----------------
__global__ __launch_bounds__(256) void expire_kernel(const float* __restrict__ mem_d,
                                                     const float* __restrict__ eW,
                                                     const float* __restrict__ eb,
                                                     float* __restrict__ exps,
                                                     float* __restrict__ aux) {
    int row = blockIdx.x;
    int tid = threadIdx.x;
    const float4 v = *(const float4*)(mem_d + (size_t)row * DIMC + tid * 4);
    const float4 w = *(const float4*)(eW + tid * 4);
    float s = v.x * w.x + v.y * w.y + v.z * w.z + v.w * w.w;
    for (int off = 32; off; off >>= 1) s += __shfl_down(s, off, 64);
    __shared__ float ss[4];
    int wid = tid >> 6, lane = tid & 63;
    if (lane == 0) ss[wid] = s;
    __syncthreads();
    if (tid == 0) {
        float z = ss[0] + ss[1] + ss[2] + ss[3] + eb[0];
        float e = (float)MC / (1.0f + expf(-z));
        exps[row] = e;
        atomicAdd(aux, e * (1e-6f / (float)SEQC));
    }
}

// ---------------- LayerNorm (fp32 in, bf16 out) ----------------
__global__ __launch_bounds__(256) void ln_kernel(const float* __restrict__ in,
                                                 const float* __restrict__ g,
                                                 const float* __restrict__ b,
                                                 unsigned short* __restrict__ outb) {
    int row = blockIdx.x;
    int tid = threadIdx.x;
    const float4 v = *(const float4*)(in + (size_t)row * DIMC + tid * 4);
    float s = v.x + v.y + v.z + v.w;
    float q = v.x * v.x + v.y * v.y + v.z * v.z + v.w * v.w;
    for (int off = 32; off; off >>= 1) {
        s += __shfl_down(s, off, 64);
        q += __shfl_down(q, off, 64);
    }
    __shared__ float ss[4], sq[4];
    int wid = tid >> 6, lane = tid & 63;
    if (lane == 0) { ss[wid] = s; sq[wid] = q; }
    __syncthreads();
    if (tid == 0) {
        float S = ss[0] + ss[1] + ss[2] + ss[3];
        float Q = sq[0] + sq[1] + sq[2] + sq[3];
        float mu = S / DIMC;
        float var = Q / DIMC - mu * mu;
        ss[0] = mu;
        sq[0] = rsqrtf(var + 1e-5f);
    }
    __syncthreads();
    float mu = ss[0], rstd = sq[0];
    const float4 gg = *(const float4*)(g + tid * 4);
    const float4 bb = *(const float4*)(b + tid * 4);
    u16x4 o = { f2bf((v.x - mu) * rstd * gg.x + bb.x),
                f2bf((v.y - mu) * rstd * gg.y + bb.y),
                f2bf((v.z - mu) * rstd * gg.z + bb.z),
                f2bf((v.w - mu) * rstd * gg.w + bb.w) };
    *(u16x4*)(outb + (size_t)row * DIMC + tid * 4) = o;
}

// ---------------- weight convert + transpose: fp32 [K][N] -> bf16 [N][K] ----------------
__global__ __launch_bounds__(256) void wt_kernel(const float* __restrict__ W,
                                                 unsigned short* __restrict__ Wt,
                                                 int K, int N) {
    __shared__ float t[32][33];
    int tid = threadIdx.x;
    int n0 = blockIdx.x * 32, k0 = blockIdx.y * 32;
    int r = tid >> 3, c = (tid & 7) * 4;
    const float4 v = *(const float4*)(W + (size_t)(k0 + r) * N + n0 + c);
    t[r][c] = v.x; t[r][c + 1] = v.y; t[r][c + 2] = v.z; t[r][c + 3] = v.w;
    __syncthreads();
    u16x4 o = { f2bf(t[c + 0][r]), f2bf(t[c + 1][r]),
                f2bf(t[c + 2][r]), f2bf(t[c + 3][r]) };
    *(u16x4*)(Wt + (size_t)(n0 + r) * K + k0 + c) = o;
}

// ---------------- fp32 -> bf16 elementwise ----------------
__global__ __launch_bounds__(256) void f2b_kernel(const float* __restrict__ in,
                                                  unsigned short* __restrict__ out, int n4) {
    int i = blockIdx.x * 256 + threadIdx.x;
    if (i >= n4) return;
    float4 v = *(const float4*)(in + (size_t)i * 4);
    u16x4 o = { f2bf(v.x), f2bf(v.y), f2bf(v.z), f2bf(v.w) };
    *(u16x4*)(out + (size_t)i * 4) = o;
}

// ---------------- bf16 MFMA GEMM (m97 structure): C = act(A @ Wt^T + bias) + res ----------------
// A: bf16 [rows][K] (GATHER: concat(mem,xn) per batch), Wt: bf16 [N][K]
// 128x128 tile, BK=32, 4 waves x (4x4) 16x16x32 fragments.
template<bool GATHER, bool BIAS, bool GELU, bool RES, bool OF32, bool OB16>
__global__ __launch_bounds__(256) void mfma_gemm(
    const unsigned short* __restrict__ A, const unsigned short* __restrict__ A2,
    const unsigned short* __restrict__ Wt, const float* __restrict__ bias,
    const float* __restrict__ res, float* __restrict__ Cf,
    unsigned short* __restrict__ Cb, int K, int N) {
    __shared__ unsigned short As[128 * 32];
    __shared__ unsigned short Bs[128 * 32];
    const int tid = threadIdx.x;
    const int lane = tid & 63, wave = tid >> 6;
    const int row0 = blockIdx.y * 128, col0 = blockIdx.x * 128;

    // staging: linear slot = p*256 + tid -> LDS row = slot>>2, 16B seg = slot&3
    const int seg = tid & 3;
    const int rr0 = tid >> 2;
    const unsigned short* arow[2];
    const unsigned short* brow[2];
    #pragma unroll
    for (int p = 0; p < 2; ++p) {
        int r = row0 + p * 64 + rr0;
        if (GATHER) {
            int b = r / CTXC, rm = r - b * CTXC;
            arow[p] = (rm < MC) ? A + ((size_t)(b * MC + rm)) * K
                                : A2 + ((size_t)(b * SEQC + rm - MC)) * K;
        } else {
            arow[p] = A + (size_t)r * K;
        }
        brow[p] = Wt + (size_t)(col0 + p * 64 + rr0) * K;
        arow[p] += seg * 8;
        brow[p] += seg * 8;
    }
    // wave-uniform LDS bases (HW adds lane*16)
    char* lA0 = (char*)As + (size_t)(tid & 192) * 16;
    char* lA1 = lA0 + 4096;
    char* lB0 = (char*)Bs + (size_t)(tid & 192) * 16;
    char* lB1 = lB0 + 4096;

    f32x4 acc[4][4] = {};

    const int wr = (wave >> 1) * 64, wc = (wave & 1) * 64;
    const int fr = lane & 15;
    const int k8 = (lane >> 4) * 8;
    const unsigned short* Ar = As + (size_t)(wr + fr) * 32 + k8;
    const unsigned short* Br = Bs + (size_t)(wc + fr) * 32 + k8;

    for (int k0 = 0; k0 < K; k0 += 32) {
        glds16(arow[0] + k0, lA0);
        glds16(arow[1] + k0, lA1);
        glds16(brow[0] + k0, lB0);
        glds16(brow[1] + k0, lB1);
        __syncthreads();
        short8 a[4], b[4];
        #pragma unroll
        for (int m = 0; m < 4; ++m) a[m] = *(const short8*)(Ar + m * 16 * 32);
        #pragma unroll
        for (int n = 0; n < 4; ++n) b[n] = *(const short8*)(Br + n * 16 * 32);
        #pragma unroll
        for (int m = 0; m < 4; ++m)
            #pragma unroll
            for (int n = 0; n < 4; ++n)
                acc[m][n] = __builtin_amdgcn_mfma_f32_16x16x32_bf16(a[m], b[n], acc[m][n], 0, 0, 0);
        __syncthreads();
    }

    // epilogue: C/D layout col=lane&15, row=(lane>>4)*4+i
    const int orow = row0 + wr + (lane >> 4) * 4;
    const int ocol = col0 + wc + fr;
    #pragma unroll
    for (int n = 0; n < 4; ++n) {
        int c = ocol + n * 16;
        float bv = BIAS ? bias[c] : 0.0f;
        #pragma unroll
        for (int m = 0; m < 4; ++m) {
            #pragma unroll
            for (int i = 0; i < 4; ++i) {
                size_t idx = (size_t)(orow + m * 16 + i) * N + c;
                float v = acc[m][n][i] + bv;
                if (GELU) v = 0.5f * v * (1.0f + erff(v * 0.70710678118f));
                if (RES) v += res[idx];
                if (OF32) Cf[idx] = v;
                if (OB16) Cb[idx] = f2bf(v);
            }
        }
    }
}

// ---------------- flash attention with expire mask (fp32, bf16 out) ----------------
__global__ __launch_bounds__(256) void attn_kernel(
    const float* __restrict__ q, const float* __restrict__ kv,
    const float* __restrict__ exps, const int* __restrict__ times_d,
    unsigned short* __restrict__ outb) {
    __shared__ float k_s[64][68];
    __shared__ float v_s[64][68];
    __shared__ float p_s[32][68];
    __shared__ float em_s[64];
    int tid = threadIdx.x;
    int qt = blockIdx.x;
    int h = blockIdx.y;
    int b = blockIdx.z;
    int qloc = tid >> 3, sub = tid & 7;
    int gq = qt * 32 + qloc;

    {
        int r = tid >> 3;
        int c = (tid & 7) * 8;
        const float* qp = q + ((size_t)(b * SEQC + qt * 32 + r)) * DIMC + h * DHC + c;
        *(float4*)&p_s[r][c] = *(const float4*)qp;
        *(float4*)&p_s[r][c + 4] = *(const float4*)(qp + 4);
    }
    __syncthreads();
    float4 qv[16];
    #pragma unroll
    for (int i = 0; i < 16; ++i) qv[i] = *(const float4*)&p_s[qloc][i * 4];

    float m = -1e30f, l = 0.0f;
    float acc[8] = {0, 0, 0, 0, 0, 0, 0, 0};
    int nkt = (MC + qt * 32 + 31) / 64 + 1;
    const float* kvb = kv + (size_t)b * CTXC * (2 * DIMC);

    for (int kt = 0; kt < nkt; ++kt) {
        int jbase = kt * 64;
        __syncthreads();
        #pragma unroll
        for (int it = 0; it < 4; ++it) {
            int f = it * 256 + tid;
            int j = f >> 4, c = (f & 15) * 4;
            const float* src = kvb + (size_t)(jbase + j) * (2 * DIMC) + h * DHC + c;
            *(float4*)&k_s[j][c] = *(const float4*)src;
            *(float4*)&v_s[j][c] = *(const float4*)(src + DIMC);
        }
        if (tid < 64) {
            int jg = jbase + tid;
            float em = 1.0f;
            if (jg < MC) {
                float rr = (exps[b * MC + jg] - (float)times_d[jg]) * (1.0f / 128.0f) + 1.0f;
                em = fminf(fmaxf(rr, 0.0f), 1.0f);
            }
            em_s[tid] = em;
        }
        __syncthreads();

        float p[8];
        float mx = -1e30f;
        #pragma unroll
        for (int it = 0; it < 8; ++it) {
            int jloc = it * 8 + sub;
            int jg = jbase + jloc;
            float4 d4 = {0, 0, 0, 0};
            #pragma unroll
            for (int i = 0; i < 16; ++i) {
                float4 kk4 = *(const float4*)&k_s[jloc][i * 4];
                d4.x += qv[i].x * kk4.x;
                d4.y += qv[i].y * kk4.y;
                d4.z += qv[i].z * kk4.z;
                d4.w += qv[i].w * kk4.w;
            }
            float s = (d4.x + d4.y + d4.z + d4.w) * 0.125f;
            s = (jg <= gq + MC) ? s : -1e30f;
            p[it] = s;
            mx = fmaxf(mx, s);
        }
        mx = fmaxf(mx, __shfl_xor(mx, 1, 64));
        mx = fmaxf(mx, __shfl_xor(mx, 2, 64));
        mx = fmaxf(mx, __shfl_xor(mx, 4, 64));
        float mnew = fmaxf(m, mx);
        float f = expf(m - mnew);
        float psum = 0.0f;
        #pragma unroll
        for (int it = 0; it < 8; ++it) {
            float pe = expf(p[it] - mnew);
            p[it] = pe;
            psum += pe;
        }
        psum += __shfl_xor(psum, 1, 64);
        psum += __shfl_xor(psum, 2, 64);
        psum += __shfl_xor(psum, 4, 64);
        l = l * f + psum;
        #pragma unroll
        for (int i = 0; i < 8; ++i) acc[i] *= f;
        m = mnew;
        #pragma unroll
        for (int it = 0; it < 8; ++it) {
            int jloc = it * 8 + sub;
            p_s[qloc][jloc] = p[it] * em_s[jloc];
        }
        __syncthreads();
        #pragma unroll
        for (int j = 0; j < 64; ++j) {
            float pv = p_s[qloc][j];
            float4 v0 = *(const float4*)&v_s[j][sub * 8];
            float4 v1 = *(const float4*)&v_s[j][sub * 8 + 4];
            acc[0] += pv * v0.x; acc[1] += pv * v0.y;
            acc[2] += pv * v0.z; acc[3] += pv * v0.w;
            acc[4] += pv * v1.x; acc[5] += pv * v1.y;
            acc[6] += pv * v1.z; acc[7] += pv * v1.w;
        }
    }
    float inv = 1.0f / l;
    u16x8 o = { f2bf(acc[0] * inv), f2bf(acc[1] * inv), f2bf(acc[2] * inv), f2bf(acc[3] * inv),
                f2bf(acc[4] * inv), f2bf(acc[5] * inv), f2bf(acc[6] * inv), f2bf(acc[7] * inv) };
    unsigned short* op = outb + ((size_t)(b * SEQC + gq)) * DIMC + h * DHC + sub * 8;
    *(u16x8*)op = o;
}

// ---------------- aux writeback ----------------
__global__ void aux_write_kernel(const float* __restrict__ aux, float* __restrict__ dst) {
    dst[0] = aux[0];
}

extern "C" void kernel_launch(void* const* d_in, const int* in_sizes, int n_in,
                              void* d_out, int out_size, void* d_ws, size_t ws_size,
                              hipStream_t stream) {
    const int*   tokens    = (const int*)d_in[0];
    const float* mems      = (const float*)d_in[1];
    const int*   times     = (const int*)d_in[2];
    const float* token_emb = (const float*)d_in[3];
    const float* expire_W  = (const float*)d_in[4];
    const float* expire_b  = (const float*)d_in[5];
    const float* ln1_g     = (const float*)d_in[6];
    const float* ln1_b     = (const float*)d_in[7];
    const float* Wq        = (const float*)d_in[8];
    const float* Wkv       = (const float*)d_in[9];
    const float* Wo        = (const float*)d_in[10];
    const float* bo        = (const float*)d_in[11];
    const float* ln2_g     = (const float*)d_in[12];
    const float* ln2_b     = (const float*)d_in[13];
    const float* W1        = (const float*)d_in[14];
    const float* b1        = (const float*)d_in[15];
    const float* W2        = (const float*)d_in[16];
    const float* b2        = (const float*)d_in[17];
    const float* logits_W  = (const float*)d_in[18];
    const float* logits_b  = (const float*)d_in[19];

    float* out = (float*)d_out;
    float* ws  = (float*)d_ws;

    // workspace layout (f32 slots)
    float* x    = ws;                                   // 2,097,152
    float* qb   = ws + 2097152;                         // 2,097,152
    float* kv   = ws + 4194304;                         // 20,971,520
    unsigned short* xn_b   = (unsigned short*)(ws + 25165824);  // 2,097,152 bf16
    unsigned short* attn_b = (unsigned short*)(ws + 26214400);  // 2,097,152 bf16
    unsigned short* ffn_b  = (unsigned short*)(ws + 27262976);  // 8,388,608 bf16
    unsigned short* mem_b  = (unsigned short*)(ws + 31457280);  // 8,388,608 bf16
    unsigned short* x_b    = (unsigned short*)(ws + 35651584);  // 2,097,152 bf16
    unsigned short* wq_t   = (unsigned short*)(ws + 36700160);  // 1,048,576 bf16
    unsigned short* wkv_t  = (unsigned short*)(ws + 37224448);  // 2,097,152 bf16
    unsigned short* wo_t   = (unsigned short*)(ws + 38273024);  // 1,048,576 bf16
    unsigned short* w1_t   = (unsigned short*)(ws + 38797312);  // 4,194,304 bf16
    unsigned short* w2_t   = (unsigned short*)(ws + 40894464);  // 4,194,304 bf16
    unsigned short* lw_t   = (unsigned short*)kv;               // alias (kv dead after attn)
    float* exps = ws + 42991616;                        // 8,192
    float* aux  = ws + 42999808;                        // 16

    float* out_logits = out;                // 65,536,000
    float* out_mems   = out + 65536000;     // 33,554,432
    float* out_times  = out + 99090432;     // 8,192

    embed_kernel<<<BC * SEQC, 256, 0, stream>>>(tokens, token_emb, x);
    times_init_kernel<<<32, 256, 0, stream>>>(times, out_times, aux);

    for (int d = 0; d < 4; ++d) {
        const float* mem_d = mems + (size_t)d * BC * MC * DIMC;
        newmem_kernel<<<8192, 256, 0, stream>>>(mem_d, x, out_mems + (size_t)d * BC * MC * DIMC);
        expire_kernel<<<BC * MC, 256, 0, stream>>>(mem_d, expire_W + d * DIMC, expire_b + d, exps, aux);
        f2b_kernel<<<8192, 256, 0, stream>>>(mem_d, mem_b, 2097152);
        ln_kernel<<<BC * SEQC, 256, 0, stream>>>(x, ln1_g + d * DIMC, ln1_b + d * DIMC, xn_b);

        wt_kernel<<<dim3(32, 32), 256, 0, stream>>>(Wq + (size_t)d * DIMC * DIMC, wq_t, DIMC, DIMC);
        wt_kernel<<<dim3(64, 32), 256, 0, stream>>>(Wkv + (size_t)d * DIMC * 2 * DIMC, wkv_t, DIMC, 2 * DIMC);
        wt_kernel<<<dim3(32, 32), 256, 0, stream>>>(Wo + (size_t)d * DIMC * DIMC, wo_t, DIMC, DIMC);
        wt_kernel<<<dim3(128, 32), 256, 0, stream>>>(W1 + (size_t)d * DIMC * 4 * DIMC, w1_t, DIMC, 4 * DIMC);
        wt_kernel<<<dim3(32, 128), 256, 0, stream>>>(W2 + (size_t)d * 4 * DIMC * DIMC, w2_t, 4 * DIMC, DIMC);

        mfma_gemm<false, false, false, false, true, false><<<dim3(8, 16), 256, 0, stream>>>(
            xn_b, nullptr, wq_t, nullptr, nullptr, qb, nullptr, DIMC, DIMC);
        mfma_gemm<true, false, false, false, true, false><<<dim3(16, 80), 256, 0, stream>>>(
            mem_b, xn_b, wkv_t, nullptr, nullptr, kv, nullptr, DIMC, 2 * DIMC);
        attn_kernel<<<dim3(16, HEADSC, BC), 256, 0, stream>>>(qb, kv, exps, times + d * MC, attn_b);
        mfma_gemm<false, true, false, true, true, false><<<dim3(8, 16), 256, 0, stream>>>(
            attn_b, nullptr, wo_t, bo + d * DIMC, x, x, nullptr, DIMC, DIMC);
        ln_kernel<<<BC * SEQC, 256, 0, stream>>>(x, ln2_g + d * DIMC, ln2_b + d * DIMC, xn_b);
        mfma_gemm<false, true, true, false, false, true><<<dim3(32, 16), 256, 0, stream>>>(
            xn_b, nullptr, w1_t, b1 + d * 4 * DIMC, nullptr, nullptr, ffn_b, DIMC, 4 * DIMC);
        mfma_gemm<false, true, false, true, true, false><<<dim3(8, 16), 256, 0, stream>>>(
            ffn_b, nullptr, w2_t, b2 + d * DIMC, x, x, nullptr, 4 * DIMC, DIMC);
    }

    f2b_kernel<<<2048, 256, 0, stream>>>(x, x_b, 524288);
    wt_kernel<<<dim3(1000, 32), 256, 0, stream>>>(logits_W, lw_t, DIMC, VOCABC);
    mfma_gemm<false, true, false, false, true, false><<<dim3(250, 16), 256, 0, stream>>>(
        x_b, nullptr, lw_t, logits_b, nullptr, out_logits, nullptr, DIMC, VOCABC);
    aux_write_kernel<<<1, 1, 0, stream>>>(aux, out + 99098624);
}

// Round 3
// 2257.207 us; speedup vs baseline: 4.3305x; 1.6675x over previous
//
#include <hip/hip_runtime.h>
#include <cmath>

// Problem constants
#define DIMC   1024
#define SEQC   512
#define BC     4
#define MC     2048      // MAXMEM
#define CTXC   2560      // MC + SEQC
#define HEADSC 16
#define DHC    64
#define VOCABC 32000

using short8 = __attribute__((ext_vector_type(8))) short;
using f32x4  = __attribute__((ext_vector_type(4))) float;
using u16x4  = __attribute__((ext_vector_type(4))) unsigned short;
using u16x8  = __attribute__((ext_vector_type(8))) unsigned short;

__device__ __forceinline__ unsigned short f2bf(float f) {
    unsigned u = __float_as_uint(f);
    unsigned r = (u + 0x7fffu + ((u >> 16) & 1u)) >> 16;
    return (unsigned short)r;
}

__device__ __forceinline__ void glds16(const unsigned short* g, char* l) {
    __builtin_amdgcn_global_load_lds(
        (const __attribute__((address_space(1))) void*)g,
        (__attribute__((address_space(3))) void*)l, 16, 0, 0);
}

// ---------------- embed ----------------
__global__ __launch_bounds__(256) void embed_kernel(const int* __restrict__ tokens,
                                                    const float* __restrict__ emb,
                                                    float* __restrict__ x) {
    int row = blockIdx.x;
    int tok = tokens[row];
    const float4 v = *(const float4*)(emb + (size_t)tok * DIMC + threadIdx.x * 4);
    *(float4*)(x + (size_t)row * DIMC + threadIdx.x * 4) = v;
}

// ---------------- new_times + aux zero ----------------
__global__ __launch_bounds__(256) void times_init_kernel(const int* __restrict__ times,
                                                         float* __restrict__ out_times,
                                                         float* __restrict__ aux) {
    int i = blockIdx.x * 256 + threadIdx.x;
    if (i == 0) aux[0] = 0.0f;
    if (i < 4 * MC) {
        int d = i >> 11, m = i & (MC - 1);
        out_times[i] = (m < MC - SEQC) ? (float)(times[d * MC + SEQC + m] + SEQC)
                                       : (float)(MC - 1 - m);
    }
}

// ---------------- new_mems ----------------
__global__ __launch_bounds__(256) void newmem_kernel(const float* __restrict__ mem_d,
                                                     const float* __restrict__ x,
                                                     float* __restrict__ out) {
    size_t i = (size_t)blockIdx.x * 256 + threadIdx.x;
    int c4 = (int)(i & 255);
    size_t rowi = i >> 8;
    int m = (int)(rowi & (MC - 1));
    int b = (int)(rowi >> 11);
    const float* src = (m < MC - SEQC)
        ? mem_d + ((size_t)(b * MC + m + SEQC)) * DIMC
        : x + ((size_t)(b * SEQC + m - (MC - SEQC))) * DIMC;
    *(float4*)(out + rowi * DIMC + c4 * 4) = *(const float4*)(src + c4 * 4);
}

// ---------------- expire span ----------------
__global__ __launch_bounds__(256) void expire_kernel(const float* __restrict__ mem_d,
                                                     const float* __restrict__ eW,
                                                     const float* __restrict__ eb,
                                                     float* __restrict__ exps,
                                                     float* __restrict__ aux) {
    int row = blockIdx.x;
    int tid = threadIdx.x;
    const float4 v = *(const float4*)(mem_d + (size_t)row * DIMC + tid * 4);
    const float4 w = *(const float4*)(eW + tid * 4);
    float s = v.x * w.x + v.y * w.y + v.z * w.z + v.w * w.w;
    for (int off = 32; off; off >>= 1) s += __shfl_down(s, off, 64);
    __shared__ float ss[4];
    int wid = tid >> 6, lane = tid & 63;
    if (lane == 0) ss[wid] = s;
    __syncthreads();
    if (tid == 0) {
        float z = ss[0] + ss[1] + ss[2] + ss[3] + eb[0];
        float e = (float)MC / (1.0f + expf(-z));
        exps[row] = e;
        atomicAdd(aux, e * (1e-6f / (float)SEQC));
    }
}

// ---------------- LayerNorm (fp32 in, bf16 out) ----------------
__global__ __launch_bounds__(256) void ln_kernel(const float* __restrict__ in,
                                                 const float* __restrict__ g,
                                                 const float* __restrict__ b,
                                                 unsigned short* __restrict__ outb) {
    int row = blockIdx.x;
    int tid = threadIdx.x;
    const float4 v = *(const float4*)(in + (size_t)row * DIMC + tid * 4);
    float s = v.x + v.y + v.z + v.w;
    float q = v.x * v.x + v.y * v.y + v.z * v.z + v.w * v.w;
    for (int off = 32; off; off >>= 1) {
        s += __shfl_down(s, off, 64);
        q += __shfl_down(q, off, 64);
    }
    __shared__ float ss[4], sq[4];
    int wid = tid >> 6, lane = tid & 63;
    if (lane == 0) { ss[wid] = s; sq[wid] = q; }
    __syncthreads();
    if (tid == 0) {
        float S = ss[0] + ss[1] + ss[2] + ss[3];
        float Q = sq[0] + sq[1] + sq[2] + sq[3];
        float mu = S / DIMC;
        float var = Q / DIMC - mu * mu;
        ss[0] = mu;
        sq[0] = rsqrtf(var + 1e-5f);
    }
    __syncthreads();
    float mu = ss[0], rstd = sq[0];
    const float4 gg = *(const float4*)(g + tid * 4);
    const float4 bb = *(const float4*)(b + tid * 4);
    u16x4 o = { f2bf((v.x - mu) * rstd * gg.x + bb.x),
                f2bf((v.y - mu) * rstd * gg.y + bb.y),
                f2bf((v.z - mu) * rstd * gg.z + bb.z),
                f2bf((v.w - mu) * rstd * gg.w + bb.w) };
    *(u16x4*)(outb + (size_t)row * DIMC + tid * 4) = o;
}

// ---------------- weight convert + transpose: fp32 [K][N] -> bf16 [N][K] ----------------
__global__ __launch_bounds__(256) void wt_kernel(const float* __restrict__ W,
                                                 unsigned short* __restrict__ Wt,
                                                 int K, int N) {
    __shared__ float t[32][33];
    int tid = threadIdx.x;
    int n0 = blockIdx.x * 32, k0 = blockIdx.y * 32;
    int r = tid >> 3, c = (tid & 7) * 4;
    const float4 v = *(const float4*)(W + (size_t)(k0 + r) * N + n0 + c);
    t[r][c] = v.x; t[r][c + 1] = v.y; t[r][c + 2] = v.z; t[r][c + 3] = v.w;
    __syncthreads();
    u16x4 o = { f2bf(t[c + 0][r]), f2bf(t[c + 1][r]),
                f2bf(t[c + 2][r]), f2bf(t[c + 3][r]) };
    *(u16x4*)(Wt + (size_t)(n0 + r) * K + k0 + c) = o;
}

// ---------------- fp32 -> bf16 elementwise ----------------
__global__ __launch_bounds__(256) void f2b_kernel(const float* __restrict__ in,
                                                  unsigned short* __restrict__ out, int n4) {
    int i = blockIdx.x * 256 + threadIdx.x;
    if (i >= n4) return;
    float4 v = *(const float4*)(in + (size_t)i * 4);
    u16x4 o = { f2bf(v.x), f2bf(v.y), f2bf(v.z), f2bf(v.w) };
    *(u16x4*)(out + (size_t)i * 4) = o;
}

// ---------------- V transpose: kv_b V-half [b][ctx][1024..2047] -> vT [b][c][ctx] ----------------
__global__ __launch_bounds__(256) void vt_kernel(const unsigned short* __restrict__ kvb,
                                                 unsigned short* __restrict__ vT) {
    __shared__ unsigned short t[64][72];
    int jt = blockIdx.x, dt = blockIdx.y, b = blockIdx.z;
    int tid = threadIdx.x;
    int r = tid >> 3, c = (tid & 7) * 8;
    #pragma unroll
    for (int p = 0; p < 2; ++p) {
        u16x8 v = *(const u16x8*)(kvb + ((size_t)(b * CTXC + jt * 64 + r + p * 32)) * 2048
                                  + 1024 + dt * 64 + c);
        *(u16x8*)&t[r + p * 32][c] = v;
    }
    __syncthreads();
    #pragma unroll
    for (int p = 0; p < 2; ++p) {
        int dr = r + p * 32;
        u16x8 o = { t[c + 0][dr], t[c + 1][dr], t[c + 2][dr], t[c + 3][dr],
                    t[c + 4][dr], t[c + 5][dr], t[c + 6][dr], t[c + 7][dr] };
        *(u16x8*)(vT + ((size_t)(b * 1024 + dt * 64 + dr)) * CTXC + jt * 64 + c) = o;
    }
}

// ---------------- bf16 MFMA GEMM (m97 structure) ----------------
template<bool GATHER, bool BIAS, bool GELU, bool RES, bool OF32, bool OB16>
__global__ __launch_bounds__(256) void mfma_gemm(
    const unsigned short* __restrict__ A, const unsigned short* __restrict__ A2,
    const unsigned short* __restrict__ Wt, const float* __restrict__ bias,
    const float* __restrict__ res, float* __restrict__ Cf,
    unsigned short* __restrict__ Cb, int K, int N) {
    __shared__ unsigned short As[128 * 32];
    __shared__ unsigned short Bs[128 * 32];
    const int tid = threadIdx.x;
    const int lane = tid & 63, wave = tid >> 6;
    const int row0 = blockIdx.y * 128, col0 = blockIdx.x * 128;

    const int seg = tid & 3;
    const int rr0 = tid >> 2;
    const unsigned short* arow[2];
    const unsigned short* brow[2];
    #pragma unroll
    for (int p = 0; p < 2; ++p) {
        int r = row0 + p * 64 + rr0;
        if (GATHER) {
            int b = r / CTXC, rm = r - b * CTXC;
            arow[p] = (rm < MC) ? A + ((size_t)(b * MC + rm)) * K
                                : A2 + ((size_t)(b * SEQC + rm - MC)) * K;
        } else {
            arow[p] = A + (size_t)r * K;
        }
        brow[p] = Wt + (size_t)(col0 + p * 64 + rr0) * K;
        arow[p] += seg * 8;
        brow[p] += seg * 8;
    }
    char* lA0 = (char*)As + (size_t)(tid & 192) * 16;
    char* lA1 = lA0 + 4096;
    char* lB0 = (char*)Bs + (size_t)(tid & 192) * 16;
    char* lB1 = lB0 + 4096;

    f32x4 acc[4][4] = {};

    const int wr = (wave >> 1) * 64, wc = (wave & 1) * 64;
    const int fr = lane & 15;
    const int k8 = (lane >> 4) * 8;
    const unsigned short* Ar = As + (size_t)(wr + fr) * 32 + k8;
    const unsigned short* Br = Bs + (size_t)(wc + fr) * 32 + k8;

    for (int k0 = 0; k0 < K; k0 += 32) {
        glds16(arow[0] + k0, lA0);
        glds16(arow[1] + k0, lA1);
        glds16(brow[0] + k0, lB0);
        glds16(brow[1] + k0, lB1);
        __syncthreads();
        short8 a[4], b[4];
        #pragma unroll
        for (int m = 0; m < 4; ++m) a[m] = *(const short8*)(Ar + m * 16 * 32);
        #pragma unroll
        for (int n = 0; n < 4; ++n) b[n] = *(const short8*)(Br + n * 16 * 32);
        #pragma unroll
        for (int m = 0; m < 4; ++m)
            #pragma unroll
            for (int n = 0; n < 4; ++n)
                acc[m][n] = __builtin_amdgcn_mfma_f32_16x16x32_bf16(a[m], b[n], acc[m][n], 0, 0, 0);
        __syncthreads();
    }

    const int orow = row0 + wr + (lane >> 4) * 4;
    const int ocol = col0 + wc + fr;
    #pragma unroll
    for (int n = 0; n < 4; ++n) {
        int c = ocol + n * 16;
        float bv = BIAS ? bias[c] : 0.0f;
        #pragma unroll
        for (int m = 0; m < 4; ++m) {
            #pragma unroll
            for (int i = 0; i < 4; ++i) {
                size_t idx = (size_t)(orow + m * 16 + i) * N + c;
                float v = acc[m][n][i] + bv;
                if (GELU) v = 0.5f * v * (1.0f + erff(v * 0.70710678118f));
                if (RES) v += res[idx];
                if (OF32) Cf[idx] = v;
                if (OB16) Cb[idx] = f2bf(v);
            }
        }
    }
}

// ---------------- MFMA flash attention with expire mask ----------------
// block: 256 thr = 4 waves, each wave owns 16 q rows; q-tile = 64; key tiles = 64.
// K staged [key][64] swizzled; V^T staged [dh][64 keys] swizzled (both via glds16
// with source-pre-swizzle seg^=(row&7)). P round-trips LDS (72-padded).
__global__ __launch_bounds__(256) void attn_mfma_kernel(
    const unsigned short* __restrict__ qb,   // [B*SEQ][1024] bf16
    const unsigned short* __restrict__ kvb,  // [B*CTX][2048] bf16
    const unsigned short* __restrict__ vT,   // [B*1024][CTX] bf16
    const float* __restrict__ exps,          // [B*MC]
    const int* __restrict__ times_d,         // [MC]
    unsigned short* __restrict__ outb) {     // [B*SEQ][1024] bf16
    __shared__ unsigned short K_s[64 * 64];
    __shared__ unsigned short V_s[64 * 64];
    __shared__ unsigned short p_s[4][16][72];
    __shared__ float em_s[64];
    const int tid = threadIdx.x;
    const int lane = tid & 63, wave = tid >> 6;
    const int qt = blockIdx.x, h = blockIdx.y, b = blockIdx.z;
    const int fr = lane & 15, g = lane >> 4;
    const int gq = qt * 64 + wave * 16;      // wave's first q row

    // Q fragments (held in regs): row fr, k = ks*32 + g*8
    short8 aq[2];
    {
        const unsigned short* qp = qb + ((size_t)(b * SEQC + gq + fr)) * DIMC + h * DHC + g * 8;
        aq[0] = *(const short8*)qp;
        aq[1] = *(const short8*)(qp + 32);
    }

    const int sr = tid >> 3, ss = tid & 7;
    char* ldk = (char*)K_s + (tid & 192) * 16;
    char* ldv = (char*)V_s + (tid & 192) * 16;

    f32x4 acc_o[4] = {};
    float mrow[4], lrow[4];
    #pragma unroll
    for (int i = 0; i < 4; ++i) { mrow[i] = -1e30f; lrow[i] = 0.0f; }

    const int nkt = 33 + qt;

    for (int kt = 0; kt < nkt; ++kt) {
        const int jbase = kt * 64;
        __syncthreads();
        #pragma unroll
        for (int p = 0; p < 2; ++p) {
            int r = sr + p * 32;
            int sw = ((ss ^ (r & 7))) * 8;
            glds16(kvb + ((size_t)(b * CTXC + jbase + r)) * 2048 + h * DHC + sw,
                   ldk + p * 4096);
            glds16(vT + ((size_t)(b * 1024 + h * DHC + r)) * CTXC + jbase + sw,
                   ldv + p * 4096);
        }
        if (tid < 64) {
            int jg = jbase + tid;
            float em = 1.0f;
            if (jg < MC) {
                float rr = (exps[b * MC + jg] - (float)times_d[jg]) * (1.0f / 128.0f) + 1.0f;
                em = fminf(fmaxf(rr, 0.0f), 1.0f);
            }
            em_s[tid] = em;
        }
        __syncthreads();

        // S = Q @ K^T : 16 q rows x 64 keys
        f32x4 s_acc[4] = {};
        #pragma unroll
        for (int ks = 0; ks < 2; ++ks) {
            #pragma unroll
            for (int n = 0; n < 4; ++n) {
                int row = n * 16 + fr;
                int sg = (ks * 4 + g) ^ (row & 7);
                short8 bk = *(const short8*)((const char*)K_s + row * 128 + sg * 16);
                s_acc[n] = __builtin_amdgcn_mfma_f32_16x16x32_bf16(aq[ks], bk, s_acc[n], 0, 0, 0);
            }
        }

        // per-lane: key col = n*16+fr, q row = g*4+i
        float em_l[4];
        #pragma unroll
        for (int n = 0; n < 4; ++n) em_l[n] = em_s[n * 16 + fr];

        float sv[4][4];
        #pragma unroll
        for (int n = 0; n < 4; ++n) {
            int jg = jbase + n * 16 + fr;
            #pragma unroll
            for (int i = 0; i < 4; ++i) {
                float s = s_acc[n][i] * 0.125f;
                sv[n][i] = (jg <= gq + g * 4 + i + MC) ? s : -1e30f;
            }
        }
        float fs[4], mnew[4];
        #pragma unroll
        for (int i = 0; i < 4; ++i) {
            float mx = fmaxf(fmaxf(sv[0][i], sv[1][i]), fmaxf(sv[2][i], sv[3][i]));
            mx = fmaxf(mx, __shfl_xor(mx, 1, 64));
            mx = fmaxf(mx, __shfl_xor(mx, 2, 64));
            mx = fmaxf(mx, __shfl_xor(mx, 4, 64));
            mx = fmaxf(mx, __shfl_xor(mx, 8, 64));
            mnew[i] = fmaxf(mrow[i], mx);
            fs[i] = __expf(mrow[i] - mnew[i]);
            mrow[i] = mnew[i];
        }
        float psum[4] = {0.f, 0.f, 0.f, 0.f};
        #pragma unroll
        for (int n = 0; n < 4; ++n) {
            #pragma unroll
            for (int i = 0; i < 4; ++i) {
                float pe = __expf(sv[n][i] - mnew[i]);
                psum[i] += pe;
                p_s[wave][g * 4 + i][n * 16 + fr] = f2bf(pe * em_l[n]);
            }
        }
        #pragma unroll
        for (int i = 0; i < 4; ++i) {
            float ps = psum[i];
            ps += __shfl_xor(ps, 1, 64);
            ps += __shfl_xor(ps, 2, 64);
            ps += __shfl_xor(ps, 4, 64);
            ps += __shfl_xor(ps, 8, 64);
            lrow[i] = lrow[i] * fs[i] + ps;
        }
        #pragma unroll
        for (int n = 0; n < 4; ++n)
            #pragma unroll
            for (int i = 0; i < 4; ++i)
                acc_o[n][i] *= fs[i];

        asm volatile("s_waitcnt lgkmcnt(0)" ::: "memory");

        // O += P @ V : A = p_s rows, B = V^T rows
        #pragma unroll
        for (int ks = 0; ks < 2; ++ks) {
            short8 ap = *(const short8*)&p_s[wave][fr][ks * 32 + g * 8];
            #pragma unroll
            for (int n = 0; n < 4; ++n) {
                int row = n * 16 + fr;
                int sg = (ks * 4 + g) ^ (row & 7);
                short8 bv = *(const short8*)((const char*)V_s + row * 128 + sg * 16);
                acc_o[n] = __builtin_amdgcn_mfma_f32_16x16x32_bf16(ap, bv, acc_o[n], 0, 0, 0);
            }
        }
    }

    float inv[4];
    #pragma unroll
    for (int i = 0; i < 4; ++i) inv[i] = 1.0f / lrow[i];
    #pragma unroll
    for (int n = 0; n < 4; ++n) {
        #pragma unroll
        for (int i = 0; i < 4; ++i) {
            size_t idx = ((size_t)(b * SEQC + gq + g * 4 + i)) * DIMC + h * DHC + n * 16 + fr;
            outb[idx] = f2bf(acc_o[n][i] * inv[i]);
        }
    }
}

// ---------------- aux writeback ----------------
__global__ void aux_write_kernel(const float* __restrict__ aux, float* __restrict__ dst) {
    dst[0] = aux[0];
}

extern "C" void kernel_launch(void* const* d_in, const int* in_sizes, int n_in,
                              void* d_out, int out_size, void* d_ws, size_t ws_size,
                              hipStream_t stream) {
    const int*   tokens    = (const int*)d_in[0];
    const float* mems      = (const float*)d_in[1];
    const int*   times     = (const int*)d_in[2];
    const float* token_emb = (const float*)d_in[3];
    const float* expire_W  = (const float*)d_in[4];
    const float* expire_b  = (const float*)d_in[5];
    const float* ln1_g     = (const float*)d_in[6];
    const float* ln1_b     = (const float*)d_in[7];
    const float* Wq        = (const float*)d_in[8];
    const float* Wkv       = (const float*)d_in[9];
    const float* Wo        = (const float*)d_in[10];
    const float* bo        = (const float*)d_in[11];
    const float* ln2_g     = (const float*)d_in[12];
    const float* ln2_b     = (const float*)d_in[13];
    const float* W1        = (const float*)d_in[14];
    const float* b1        = (const float*)d_in[15];
    const float* W2        = (const float*)d_in[16];
    const float* b2        = (const float*)d_in[17];
    const float* logits_W  = (const float*)d_in[18];
    const float* logits_b  = (const float*)d_in[19];

    float* out = (float*)d_out;
    float* ws  = (float*)d_ws;

    // workspace layout (float slots)
    float* x = ws;                                                 // 2,097,152
    unsigned short* qb_b  = (unsigned short*)(ws + 2097152);       // 2,097,152 u16
    unsigned short* kv_b  = (unsigned short*)(ws + 3145728);       // 20,971,520 u16
    unsigned short* vT    = (unsigned short*)(ws + 13631488);      // 10,485,760 u16
    unsigned short* xn_b  = (unsigned short*)(ws + 18874368);      // 2,097,152 u16
    unsigned short* attn_b= (unsigned short*)(ws + 19922944);      // 2,097,152 u16
    unsigned short* ffn_b = (unsigned short*)(ws + 20971520);      // 8,388,608 u16
    unsigned short* mem_b = (unsigned short*)(ws + 25165824);      // 8,388,608 u16
    unsigned short* x_b   = (unsigned short*)(ws + 29360128);      // 2,097,152 u16
    unsigned short* wq_t  = (unsigned short*)(ws + 30408704);      // 1,048,576 u16
    unsigned short* wkv_t = (unsigned short*)(ws + 30932992);      // 2,097,152 u16
    unsigned short* wo_t  = (unsigned short*)(ws + 31981568);      // 1,048,576 u16
    unsigned short* w1_t  = (unsigned short*)(ws + 32505856);      // 4,194,304 u16
    unsigned short* w2_t  = (unsigned short*)(ws + 34603008);      // 4,194,304 u16
    float* exps = ws + 36700160;                                   // 8,192
    float* aux  = ws + 36708352;                                   // 16
    // logits_W^T aliases qb_b+kv_b+vT (dead after last attention): 16.78M f >= 16.38M f
    unsigned short* lw_t = (unsigned short*)(ws + 2097152);

    float* out_logits = out;                // 65,536,000
    float* out_mems   = out + 65536000;     // 33,554,432
    float* out_times  = out + 99090432;     // 8,192

    embed_kernel<<<BC * SEQC, 256, 0, stream>>>(tokens, token_emb, x);
    times_init_kernel<<<32, 256, 0, stream>>>(times, out_times, aux);

    for (int d = 0; d < 4; ++d) {
        const float* mem_d = mems + (size_t)d * BC * MC * DIMC;
        newmem_kernel<<<8192, 256, 0, stream>>>(mem_d, x, out_mems + (size_t)d * BC * MC * DIMC);
        expire_kernel<<<BC * MC, 256, 0, stream>>>(mem_d, expire_W + d * DIMC, expire_b + d, exps, aux);
        f2b_kernel<<<8192, 256, 0, stream>>>(mem_d, mem_b, 2097152);
        ln_kernel<<<BC * SEQC, 256, 0, stream>>>(x, ln1_g + d * DIMC, ln1_b + d * DIMC, xn_b);

        wt_kernel<<<dim3(32, 32), 256, 0, stream>>>(Wq + (size_t)d * DIMC * DIMC, wq_t, DIMC, DIMC);
        wt_kernel<<<dim3(64, 32), 256, 0, stream>>>(Wkv + (size_t)d * DIMC * 2 * DIMC, wkv_t, DIMC, 2 * DIMC);
        wt_kernel<<<dim3(32, 32), 256, 0, stream>>>(Wo + (size_t)d * DIMC * DIMC, wo_t, DIMC, DIMC);
        wt_kernel<<<dim3(128, 32), 256, 0, stream>>>(W1 + (size_t)d * DIMC * 4 * DIMC, w1_t, DIMC, 4 * DIMC);
        wt_kernel<<<dim3(32, 128), 256, 0, stream>>>(W2 + (size_t)d * 4 * DIMC * DIMC, w2_t, 4 * DIMC, DIMC);

        mfma_gemm<false, false, false, false, false, true><<<dim3(8, 16), 256, 0, stream>>>(
            xn_b, nullptr, wq_t, nullptr, nullptr, nullptr, qb_b, DIMC, DIMC);
        mfma_gemm<true, false, false, false, false, true><<<dim3(16, 80), 256, 0, stream>>>(
            mem_b, xn_b, wkv_t, nullptr, nullptr, nullptr, kv_b, DIMC, 2 * DIMC);
        vt_kernel<<<dim3(40, 16, BC), 256, 0, stream>>>(kv_b, vT);
        attn_mfma_kernel<<<dim3(8, HEADSC, BC), 256, 0, stream>>>(
            qb_b, kv_b, vT, exps, times + d * MC, attn_b);
        mfma_gemm<false, true, false, true, true, false><<<dim3(8, 16), 256, 0, stream>>>(
            attn_b, nullptr, wo_t, bo + d * DIMC, x, x, nullptr, DIMC, DIMC);
        ln_kernel<<<BC * SEQC, 256, 0, stream>>>(x, ln2_g + d * DIMC, ln2_b + d * DIMC, xn_b);
        mfma_gemm<false, true, true, false, false, true><<<dim3(32, 16), 256, 0, stream>>>(
            xn_b, nullptr, w1_t, b1 + d * 4 * DIMC, nullptr, nullptr, ffn_b, DIMC, 4 * DIMC);
        mfma_gemm<false, true, false, true, true, false><<<dim3(8, 16), 256, 0, stream>>>(
            ffn_b, nullptr, w2_t, b2 + d * DIMC, x, x, nullptr, 4 * DIMC, DIMC);
    }

    f2b_kernel<<<2048, 256, 0, stream>>>(x, x_b, 524288);
    wt_kernel<<<dim3(1000, 32), 256, 0, stream>>>(logits_W, lw_t, DIMC, VOCABC);
    mfma_gemm<false, true, false, false, true, false><<<dim3(250, 16), 256, 0, stream>>>(
        x_b, nullptr, lw_t, logits_b, nullptr, out_logits, nullptr, DIMC, VOCABC);
    aux_write_kernel<<<1, 1, 0, stream>>>(aux, out + 99098624);
}

// Round 4
// 1882.160 us; speedup vs baseline: 5.1935x; 1.1993x over previous
//
#include <hip/hip_runtime.h>
#include <cmath>

// Problem constants
#define DIMC   1024
#define SEQC   512
#define BC     4
#define MC     2048      // MAXMEM
#define CTXC   2560      // MC + SEQC
#define HEADSC 16
#define DHC    64
#define VOCABC 32000

using short8 = __attribute__((ext_vector_type(8))) short;
using f32x4  = __attribute__((ext_vector_type(4))) float;
using u16x4  = __attribute__((ext_vector_type(4))) unsigned short;
using u16x8  = __attribute__((ext_vector_type(8))) unsigned short;

__device__ __forceinline__ unsigned short f2bf(float f) {
    unsigned u = __float_as_uint(f);
    unsigned r = (u + 0x7fffu + ((u >> 16) & 1u)) >> 16;
    return (unsigned short)r;
}

__device__ __forceinline__ void glds16(const unsigned short* g, char* l) {
    __builtin_amdgcn_global_load_lds(
        (const __attribute__((address_space(1))) void*)g,
        (__attribute__((address_space(3))) void*)l, 16, 0, 0);
}

// ---------------- embed ----------------
__global__ __launch_bounds__(256) void embed_kernel(const int* __restrict__ tokens,
                                                    const float* __restrict__ emb,
                                                    float* __restrict__ x) {
    int row = blockIdx.x;
    int tok = tokens[row];
    const float4 v = *(const float4*)(emb + (size_t)tok * DIMC + threadIdx.x * 4);
    *(float4*)(x + (size_t)row * DIMC + threadIdx.x * 4) = v;
}

// ---------------- new_times + aux zero ----------------
__global__ __launch_bounds__(256) void times_init_kernel(const int* __restrict__ times,
                                                         float* __restrict__ out_times,
                                                         float* __restrict__ aux) {
    int i = blockIdx.x * 256 + threadIdx.x;
    if (i == 0) aux[0] = 0.0f;
    if (i < 4 * MC) {
        int d = i >> 11, m = i & (MC - 1);
        out_times[i] = (m < MC - SEQC) ? (float)(times[d * MC + SEQC + m] + SEQC)
                                       : (float)(MC - 1 - m);
    }
}

// ---------------- fused per-layer prep ----------------
// blocks [0,8192):       mem pass: expire dot -> exps/aux, mem->bf16, out_mems copy (m>=512)
// blocks [8192,10240):   out_mems tail <- x
// blocks [10240,12288):  LN1 rows -> xn_b
// blocks [12288,24576):  weight transpose tiles (Wq,Wkv,Wo,W1,W2)
#define PREP_MEM 8192
#define PREP_XC  10240
#define PREP_LN  12288
#define PREP_TOT 24576
__global__ __launch_bounds__(256) void prep_kernel(
    const float* __restrict__ mem_d, const float* __restrict__ x,
    const float* __restrict__ eW, const float* __restrict__ eb,
    float* __restrict__ exps, float* __restrict__ aux,
    unsigned short* __restrict__ mem_b, float* __restrict__ out_mems_d,
    const float* __restrict__ g1, const float* __restrict__ b1v,
    unsigned short* __restrict__ xn_b,
    const float* __restrict__ Wq, const float* __restrict__ Wkv,
    const float* __restrict__ Wo, const float* __restrict__ W1,
    const float* __restrict__ W2,
    unsigned short* __restrict__ wq_t, unsigned short* __restrict__ wkv_t,
    unsigned short* __restrict__ wo_t, unsigned short* __restrict__ w1_t,
    unsigned short* __restrict__ w2_t) {
    __shared__ float sh[1056];
    const int bid = blockIdx.x, tid = threadIdx.x;
    if (bid < PREP_MEM) {
        int row = bid;                       // b*2048 + m
        int m = row & 2047, b = row >> 11;
        const float4 v = *(const float4*)(mem_d + (size_t)row * DIMC + tid * 4);
        const float4 w = *(const float4*)(eW + tid * 4);
        float s = v.x * w.x + v.y * w.y + v.z * w.z + v.w * w.w;
        for (int off = 32; off; off >>= 1) s += __shfl_down(s, off, 64);
        int wid = tid >> 6, lane = tid & 63;
        if (lane == 0) sh[wid] = s;
        u16x4 o = { f2bf(v.x), f2bf(v.y), f2bf(v.z), f2bf(v.w) };
        *(u16x4*)(mem_b + (size_t)row * DIMC + tid * 4) = o;
        if (m >= SEQC)
            *(float4*)(out_mems_d + ((size_t)(b * MC + m - SEQC)) * DIMC + tid * 4) = v;
        __syncthreads();
        if (tid == 0) {
            float z = sh[0] + sh[1] + sh[2] + sh[3] + eb[0];
            float e = (float)MC / (1.0f + expf(-z));
            exps[row] = e;
            atomicAdd(aux, e * (1e-6f / (float)SEQC));
        }
    } else if (bid < PREP_XC) {
        int r = bid - PREP_MEM;              // b*512 + i
        int b = r >> 9, i = r & 511;
        const float4 v = *(const float4*)(x + (size_t)r * DIMC + tid * 4);
        *(float4*)(out_mems_d + ((size_t)(b * MC + MC - SEQC + i)) * DIMC + tid * 4) = v;
    } else if (bid < PREP_LN) {
        int row = bid - PREP_XC;
        const float4 v = *(const float4*)(x + (size_t)row * DIMC + tid * 4);
        float s = v.x + v.y + v.z + v.w;
        float q = v.x * v.x + v.y * v.y + v.z * v.z + v.w * v.w;
        for (int off = 32; off; off >>= 1) {
            s += __shfl_down(s, off, 64);
            q += __shfl_down(q, off, 64);
        }
        int wid = tid >> 6, lane = tid & 63;
        if (lane == 0) { sh[wid] = s; sh[4 + wid] = q; }
        __syncthreads();
        if (tid == 0) {
            float S = sh[0] + sh[1] + sh[2] + sh[3];
            float Q = sh[4] + sh[5] + sh[6] + sh[7];
            float mu = S / DIMC;
            float var = Q / DIMC - mu * mu;
            sh[8] = mu;
            sh[9] = rsqrtf(var + 1e-5f);
        }
        __syncthreads();
        float mu = sh[8], rstd = sh[9];
        const float4 gg = *(const float4*)(g1 + tid * 4);
        const float4 bb = *(const float4*)(b1v + tid * 4);
        u16x4 o = { f2bf((v.x - mu) * rstd * gg.x + bb.x),
                    f2bf((v.y - mu) * rstd * gg.y + bb.y),
                    f2bf((v.z - mu) * rstd * gg.z + bb.z),
                    f2bf((v.w - mu) * rstd * gg.w + bb.w) };
        *(u16x4*)(xn_b + (size_t)row * DIMC + tid * 4) = o;
    } else {
        int t = bid - PREP_LN;
        const float* W; unsigned short* Wt; int K, N, tx, ty;
        if (t < 1024)      { W = Wq;  Wt = wq_t;  K = 1024; N = 1024; tx = t & 31;  ty = t >> 5; }
        else if (t < 3072) { int u = t - 1024; W = Wkv; Wt = wkv_t; K = 1024; N = 2048; tx = u & 63;  ty = u >> 6; }
        else if (t < 4096) { int u = t - 3072; W = Wo;  Wt = wo_t;  K = 1024; N = 1024; tx = u & 31;  ty = u >> 5; }
        else if (t < 8192) { int u = t - 4096; W = W1;  Wt = w1_t;  K = 1024; N = 4096; tx = u & 127; ty = u >> 7; }
        else               { int u = t - 8192; W = W2;  Wt = w2_t;  K = 4096; N = 1024; tx = u & 31;  ty = u >> 5; }
        int n0 = tx * 32, k0 = ty * 32;
        int r = tid >> 3, c = (tid & 7) * 4;
        const float4 v = *(const float4*)(W + (size_t)(k0 + r) * N + n0 + c);
        sh[r * 33 + c] = v.x; sh[r * 33 + c + 1] = v.y;
        sh[r * 33 + c + 2] = v.z; sh[r * 33 + c + 3] = v.w;
        __syncthreads();
        u16x4 o = { f2bf(sh[(c + 0) * 33 + r]), f2bf(sh[(c + 1) * 33 + r]),
                    f2bf(sh[(c + 2) * 33 + r]), f2bf(sh[(c + 3) * 33 + r]) };
        *(u16x4*)(Wt + (size_t)(n0 + r) * K + k0 + c) = o;
    }
}

// ---------------- LayerNorm (fp32 in, bf16 out) — used for LN2 ----------------
__global__ __launch_bounds__(256) void ln_kernel(const float* __restrict__ in,
                                                 const float* __restrict__ g,
                                                 const float* __restrict__ b,
                                                 unsigned short* __restrict__ outb) {
    int row = blockIdx.x;
    int tid = threadIdx.x;
    const float4 v = *(const float4*)(in + (size_t)row * DIMC + tid * 4);
    float s = v.x + v.y + v.z + v.w;
    float q = v.x * v.x + v.y * v.y + v.z * v.z + v.w * v.w;
    for (int off = 32; off; off >>= 1) {
        s += __shfl_down(s, off, 64);
        q += __shfl_down(q, off, 64);
    }
    __shared__ float ss[4], sq[4];
    int wid = tid >> 6, lane = tid & 63;
    if (lane == 0) { ss[wid] = s; sq[wid] = q; }
    __syncthreads();
    if (tid == 0) {
        float S = ss[0] + ss[1] + ss[2] + ss[3];
        float Q = sq[0] + sq[1] + sq[2] + sq[3];
        float mu = S / DIMC;
        float var = Q / DIMC - mu * mu;
        ss[0] = mu;
        sq[0] = rsqrtf(var + 1e-5f);
    }
    __syncthreads();
    float mu = ss[0], rstd = sq[0];
    const float4 gg = *(const float4*)(g + tid * 4);
    const float4 bb = *(const float4*)(b + tid * 4);
    u16x4 o = { f2bf((v.x - mu) * rstd * gg.x + bb.x),
                f2bf((v.y - mu) * rstd * gg.y + bb.y),
                f2bf((v.z - mu) * rstd * gg.z + bb.z),
                f2bf((v.w - mu) * rstd * gg.w + bb.w) };
    *(u16x4*)(outb + (size_t)row * DIMC + tid * 4) = o;
}

// ---------------- weight convert + transpose (logits_W only) ----------------
__global__ __launch_bounds__(256) void wt_kernel(const float* __restrict__ W,
                                                 unsigned short* __restrict__ Wt,
                                                 int K, int N) {
    __shared__ float t[32][33];
    int tid = threadIdx.x;
    int n0 = blockIdx.x * 32, k0 = blockIdx.y * 32;
    int r = tid >> 3, c = (tid & 7) * 4;
    const float4 v = *(const float4*)(W + (size_t)(k0 + r) * N + n0 + c);
    t[r][c] = v.x; t[r][c + 1] = v.y; t[r][c + 2] = v.z; t[r][c + 3] = v.w;
    __syncthreads();
    u16x4 o = { f2bf(t[c + 0][r]), f2bf(t[c + 1][r]),
                f2bf(t[c + 2][r]), f2bf(t[c + 3][r]) };
    *(u16x4*)(Wt + (size_t)(n0 + r) * K + k0 + c) = o;
}

// ---------------- V transpose ----------------
__global__ __launch_bounds__(256) void vt_kernel(const unsigned short* __restrict__ kvb,
                                                 unsigned short* __restrict__ vT) {
    __shared__ unsigned short t[64][72];
    int jt = blockIdx.x, dt = blockIdx.y, b = blockIdx.z;
    int tid = threadIdx.x;
    int r = tid >> 3, c = (tid & 7) * 8;
    #pragma unroll
    for (int p = 0; p < 2; ++p) {
        u16x8 v = *(const u16x8*)(kvb + ((size_t)(b * CTXC + jt * 64 + r + p * 32)) * 2048
                                  + 1024 + dt * 64 + c);
        *(u16x8*)&t[r + p * 32][c] = v;
    }
    __syncthreads();
    #pragma unroll
    for (int p = 0; p < 2; ++p) {
        int dr = r + p * 32;
        u16x8 o = { t[c + 0][dr], t[c + 1][dr], t[c + 2][dr], t[c + 3][dr],
                    t[c + 4][dr], t[c + 5][dr], t[c + 6][dr], t[c + 7][dr] };
        *(u16x8*)(vT + ((size_t)(b * 1024 + dt * 64 + dr)) * CTXC + jt * 64 + c) = o;
    }
}

// ---------------- bf16 MFMA GEMM body (m97 structure, RT = row-tile 128 or 64) ----------------
template<bool GATHER, bool BIAS, bool GELU, bool RES, int RT>
__device__ __forceinline__ void gemm_body(
    unsigned short* As, unsigned short* Bs,
    const unsigned short* __restrict__ A, const unsigned short* __restrict__ A2,
    const unsigned short* __restrict__ Wt, const float* __restrict__ bias,
    const float* __restrict__ res, float* __restrict__ Cf,
    unsigned short* __restrict__ Cb, int K, int N, int bx, int by) {
    constexpr int MF = RT / 32;              // m-fragments per wave
    const int tid = threadIdx.x;
    const int lane = tid & 63, wave = tid >> 6;
    const int row0 = by * RT, col0 = bx * 128;

    const int seg = tid & 3;
    const int rr0 = tid >> 2;
    const unsigned short* arow[RT / 64];
    #pragma unroll
    for (int p = 0; p < RT / 64; ++p) {
        int r = row0 + p * 64 + rr0;
        if (GATHER) {
            int b = r / CTXC, rm = r - b * CTXC;
            arow[p] = (rm < MC) ? A + ((size_t)(b * MC + rm)) * K
                                : A2 + ((size_t)(b * SEQC + rm - MC)) * K;
        } else {
            arow[p] = A + (size_t)r * K;
        }
        arow[p] += seg * 8;
    }
    const unsigned short* brow[2];
    #pragma unroll
    for (int p = 0; p < 2; ++p)
        brow[p] = Wt + (size_t)(col0 + p * 64 + rr0) * K + seg * 8;

    char* lA0 = (char*)As + (size_t)(tid & 192) * 16;
    char* lB0 = (char*)Bs + (size_t)(tid & 192) * 16;
    char* lB1 = lB0 + 4096;

    f32x4 acc[MF][4] = {};

    const int wr = (wave >> 1) * (RT / 2), wc = (wave & 1) * 64;
    const int fr = lane & 15;
    const int k8 = (lane >> 4) * 8;
    const unsigned short* Ar = As + (size_t)(wr + fr) * 32 + k8;
    const unsigned short* Br = Bs + (size_t)(wc + fr) * 32 + k8;

    for (int k0 = 0; k0 < K; k0 += 32) {
        glds16(arow[0] + k0, lA0);
        if (RT == 128) glds16(arow[1] + k0, lA0 + 4096);
        glds16(brow[0] + k0, lB0);
        glds16(brow[1] + k0, lB1);
        __syncthreads();
        short8 a[MF], b[4];
        #pragma unroll
        for (int m = 0; m < MF; ++m) a[m] = *(const short8*)(Ar + m * 16 * 32);
        #pragma unroll
        for (int n = 0; n < 4; ++n) b[n] = *(const short8*)(Br + n * 16 * 32);
        #pragma unroll
        for (int m = 0; m < MF; ++m)
            #pragma unroll
            for (int n = 0; n < 4; ++n)
                acc[m][n] = __builtin_amdgcn_mfma_f32_16x16x32_bf16(a[m], b[n], acc[m][n], 0, 0, 0);
        __syncthreads();
    }

    const int orow = row0 + wr + (lane >> 4) * 4;
    const int ocol = col0 + wc + fr;
    #pragma unroll
    for (int n = 0; n < 4; ++n) {
        int c = ocol + n * 16;
        float bv = BIAS ? bias[c] : 0.0f;
        #pragma unroll
        for (int m = 0; m < MF; ++m) {
            #pragma unroll
            for (int i = 0; i < 4; ++i) {
                size_t idx = (size_t)(orow + m * 16 + i) * N + c;
                float v = acc[m][n][i] + bv;
                if (GELU) v = 0.5f * v * (1.0f + erff(v * 0.70710678118f));
                if (RES) v += res[idx];
                if (Cf) Cf[idx] = v;
                if (Cb) Cb[idx] = f2bf(v);
            }
        }
    }
}

// Q (128 blocks) + KV (1280 blocks) fused dispatch
__global__ __launch_bounds__(256) void qkv_gemm_kernel(
    const unsigned short* __restrict__ xn_b, const unsigned short* __restrict__ mem_b,
    const unsigned short* __restrict__ wq_t, const unsigned short* __restrict__ wkv_t,
    unsigned short* __restrict__ qb, unsigned short* __restrict__ kvb) {
    __shared__ unsigned short As[128 * 32];
    __shared__ unsigned short Bs[128 * 32];
    int id = blockIdx.x;
    if (id < 128) {
        gemm_body<false, false, false, false, 128>(As, Bs, xn_b, nullptr, wq_t,
            nullptr, nullptr, nullptr, qb, 1024, 1024, id & 7, id >> 3);
    } else {
        id -= 128;
        gemm_body<true, false, false, false, 128>(As, Bs, mem_b, xn_b, wkv_t,
            nullptr, nullptr, nullptr, kvb, 1024, 2048, id & 15, id >> 4);
    }
}

// RT=64 GEMM with bias+residual, N=1024 (Wo and FFN2)
__global__ __launch_bounds__(256) void gemm64_kernel(
    const unsigned short* __restrict__ A, const unsigned short* __restrict__ Wt,
    const float* __restrict__ bias, const float* __restrict__ res,
    float* __restrict__ Cf, unsigned short* __restrict__ Cb, int K) {
    __shared__ unsigned short As[64 * 32];
    __shared__ unsigned short Bs[128 * 32];
    gemm_body<false, true, false, true, 64>(As, Bs, A, nullptr, Wt, bias, res,
        Cf, Cb, K, 1024, blockIdx.x, blockIdx.y);
}

// FFN1: gelu, bf16 out
__global__ __launch_bounds__(256) void ffn1_kernel(
    const unsigned short* __restrict__ A, const unsigned short* __restrict__ Wt,
    const float* __restrict__ bias, unsigned short* __restrict__ Cb) {
    __shared__ unsigned short As[128 * 32];
    __shared__ unsigned short Bs[128 * 32];
    gemm_body<false, true, true, false, 128>(As, Bs, A, nullptr, Wt, bias, nullptr,
        nullptr, Cb, 1024, 4096, blockIdx.x, blockIdx.y);
}

// logits: grid (16 rows, 250 cols) — row-tile fastest for B-tile L2 reuse
__global__ __launch_bounds__(256) void logits_kernel(
    const unsigned short* __restrict__ A, const unsigned short* __restrict__ Wt,
    const float* __restrict__ bias, float* __restrict__ Cf) {
    __shared__ unsigned short As[128 * 32];
    __shared__ unsigned short Bs[128 * 32];
    gemm_body<false, true, false, false, 128>(As, Bs, A, nullptr, Wt, bias, nullptr,
        Cf, nullptr, 1024, VOCABC, blockIdx.y, blockIdx.x);
}

// ---------------- MFMA flash attention with expire mask ----------------
__global__ __launch_bounds__(256) void attn_mfma_kernel(
    const unsigned short* __restrict__ qb,
    const unsigned short* __restrict__ kvb,
    const unsigned short* __restrict__ vT,
    const float* __restrict__ exps,
    const int* __restrict__ times_d,
    unsigned short* __restrict__ outb) {
    __shared__ unsigned short K_s[64 * 64];
    __shared__ unsigned short V_s[64 * 64];
    __shared__ unsigned short p_s[4][16][72];
    __shared__ float em_s[64];
    const int tid = threadIdx.x;
    const int lane = tid & 63, wave = tid >> 6;
    const int qt = blockIdx.x, h = blockIdx.y, b = blockIdx.z;
    const int fr = lane & 15, g = lane >> 4;
    const int gq = qt * 64 + wave * 16;

    short8 aq[2];
    {
        const unsigned short* qp = qb + ((size_t)(b * SEQC + gq + fr)) * DIMC + h * DHC + g * 8;
        aq[0] = *(const short8*)qp;
        aq[1] = *(const short8*)(qp + 32);
    }

    const int sr = tid >> 3, ss = tid & 7;
    char* ldk = (char*)K_s + (tid & 192) * 16;
    char* ldv = (char*)V_s + (tid & 192) * 16;

    f32x4 acc_o[4] = {};
    float mrow[4], lrow[4];
    #pragma unroll
    for (int i = 0; i < 4; ++i) { mrow[i] = -1e30f; lrow[i] = 0.0f; }

    const int nkt = 33 + qt;

    for (int kt = 0; kt < nkt; ++kt) {
        const int jbase = kt * 64;
        __syncthreads();
        #pragma unroll
        for (int p = 0; p < 2; ++p) {
            int r = sr + p * 32;
            int sw = ((ss ^ (r & 7))) * 8;
            glds16(kvb + ((size_t)(b * CTXC + jbase + r)) * 2048 + h * DHC + sw,
                   ldk + p * 4096);
            glds16(vT + ((size_t)(b * 1024 + h * DHC + r)) * CTXC + jbase + sw,
                   ldv + p * 4096);
        }
        if (tid < 64) {
            int jg = jbase + tid;
            float em = 1.0f;
            if (jg < MC) {
                float rr = (exps[b * MC + jg] - (float)times_d[jg]) * (1.0f / 128.0f) + 1.0f;
                em = fminf(fmaxf(rr, 0.0f), 1.0f);
            }
            em_s[tid] = em;
        }
        __syncthreads();

        f32x4 s_acc[4] = {};
        #pragma unroll
        for (int ks = 0; ks < 2; ++ks) {
            #pragma unroll
            for (int n = 0; n < 4; ++n) {
                int row = n * 16 + fr;
                int sg = (ks * 4 + g) ^ (row & 7);
                short8 bk = *(const short8*)((const char*)K_s + row * 128 + sg * 16);
                s_acc[n] = __builtin_amdgcn_mfma_f32_16x16x32_bf16(aq[ks], bk, s_acc[n], 0, 0, 0);
            }
        }

        float em_l[4];
        #pragma unroll
        for (int n = 0; n < 4; ++n) em_l[n] = em_s[n * 16 + fr];

        float sv[4][4];
        #pragma unroll
        for (int n = 0; n < 4; ++n) {
            int jg = jbase + n * 16 + fr;
            #pragma unroll
            for (int i = 0; i < 4; ++i) {
                float s = s_acc[n][i] * 0.125f;
                sv[n][i] = (jg <= gq + g * 4 + i + MC) ? s : -1e30f;
            }
        }
        float fs[4], mnew[4];
        #pragma unroll
        for (int i = 0; i < 4; ++i) {
            float mx = fmaxf(fmaxf(sv[0][i], sv[1][i]), fmaxf(sv[2][i], sv[3][i]));
            mx = fmaxf(mx, __shfl_xor(mx, 1, 64));
            mx = fmaxf(mx, __shfl_xor(mx, 2, 64));
            mx = fmaxf(mx, __shfl_xor(mx, 4, 64));
            mx = fmaxf(mx, __shfl_xor(mx, 8, 64));
            mnew[i] = fmaxf(mrow[i], mx);
            fs[i] = __expf(mrow[i] - mnew[i]);
            mrow[i] = mnew[i];
        }
        float psum[4] = {0.f, 0.f, 0.f, 0.f};
        #pragma unroll
        for (int n = 0; n < 4; ++n) {
            #pragma unroll
            for (int i = 0; i < 4; ++i) {
                float pe = __expf(sv[n][i] - mnew[i]);
                psum[i] += pe;
                p_s[wave][g * 4 + i][n * 16 + fr] = f2bf(pe * em_l[n]);
            }
        }
        #pragma unroll
        for (int i = 0; i < 4; ++i) {
            float ps = psum[i];
            ps += __shfl_xor(ps, 1, 64);
            ps += __shfl_xor(ps, 2, 64);
            ps += __shfl_xor(ps, 4, 64);
            ps += __shfl_xor(ps, 8, 64);
            lrow[i] = lrow[i] * fs[i] + ps;
        }
        #pragma unroll
        for (int n = 0; n < 4; ++n)
            #pragma unroll
            for (int i = 0; i < 4; ++i)
                acc_o[n][i] *= fs[i];

        asm volatile("s_waitcnt lgkmcnt(0)" ::: "memory");

        #pragma unroll
        for (int ks = 0; ks < 2; ++ks) {
            short8 ap = *(const short8*)&p_s[wave][fr][ks * 32 + g * 8];
            #pragma unroll
            for (int n = 0; n < 4; ++n) {
                int row = n * 16 + fr;
                int sg = (ks * 4 + g) ^ (row & 7);
                short8 bv = *(const short8*)((const char*)V_s + row * 128 + sg * 16);
                acc_o[n] = __builtin_amdgcn_mfma_f32_16x16x32_bf16(ap, bv, acc_o[n], 0, 0, 0);
            }
        }
    }

    float inv[4];
    #pragma unroll
    for (int i = 0; i < 4; ++i) inv[i] = 1.0f / lrow[i];
    #pragma unroll
    for (int n = 0; n < 4; ++n) {
        #pragma unroll
        for (int i = 0; i < 4; ++i) {
            size_t idx = ((size_t)(b * SEQC + gq + g * 4 + i)) * DIMC + h * DHC + n * 16 + fr;
            outb[idx] = f2bf(acc_o[n][i] * inv[i]);
        }
    }
}

// ---------------- aux writeback ----------------
__global__ void aux_write_kernel(const float* __restrict__ aux, float* __restrict__ dst) {
    dst[0] = aux[0];
}

extern "C" void kernel_launch(void* const* d_in, const int* in_sizes, int n_in,
                              void* d_out, int out_size, void* d_ws, size_t ws_size,
                              hipStream_t stream) {
    const int*   tokens    = (const int*)d_in[0];
    const float* mems      = (const float*)d_in[1];
    const int*   times     = (const int*)d_in[2];
    const float* token_emb = (const float*)d_in[3];
    const float* expire_W  = (const float*)d_in[4];
    const float* expire_b  = (const float*)d_in[5];
    const float* ln1_g     = (const float*)d_in[6];
    const float* ln1_b     = (const float*)d_in[7];
    const float* Wq        = (const float*)d_in[8];
    const float* Wkv       = (const float*)d_in[9];
    const float* Wo        = (const float*)d_in[10];
    const float* bo        = (const float*)d_in[11];
    const float* ln2_g     = (const float*)d_in[12];
    const float* ln2_b     = (const float*)d_in[13];
    const float* W1        = (const float*)d_in[14];
    const float* b1        = (const float*)d_in[15];
    const float* W2        = (const float*)d_in[16];
    const float* b2        = (const float*)d_in[17];
    const float* logits_W  = (const float*)d_in[18];
    const float* logits_b  = (const float*)d_in[19];

    float* out = (float*)d_out;
    float* ws  = (float*)d_ws;

    // workspace layout (float slots)
    float* x = ws;                                                 // 2,097,152
    unsigned short* qb_b  = (unsigned short*)(ws + 2097152);       // 2,097,152 u16
    unsigned short* kv_b  = (unsigned short*)(ws + 3145728);       // 20,971,520 u16
    unsigned short* vT    = (unsigned short*)(ws + 13631488);      // 10,485,760 u16
    unsigned short* xn_b  = (unsigned short*)(ws + 18874368);      // 2,097,152 u16
    unsigned short* attn_b= (unsigned short*)(ws + 19922944);      // 2,097,152 u16
    unsigned short* ffn_b = (unsigned short*)(ws + 20971520);      // 8,388,608 u16
    unsigned short* mem_b = (unsigned short*)(ws + 25165824);      // 8,388,608 u16
    unsigned short* x_b   = (unsigned short*)(ws + 29360128);      // 2,097,152 u16
    unsigned short* wq_t  = (unsigned short*)(ws + 30408704);      // 1,048,576 u16
    unsigned short* wkv_t = (unsigned short*)(ws + 30932992);      // 2,097,152 u16
    unsigned short* wo_t  = (unsigned short*)(ws + 31981568);      // 1,048,576 u16
    unsigned short* w1_t  = (unsigned short*)(ws + 32505856);      // 4,194,304 u16
    unsigned short* w2_t  = (unsigned short*)(ws + 34603008);      // 4,194,304 u16
    float* exps = ws + 36700160;                                   // 8,192
    float* aux  = ws + 36708352;                                   // 16
    // logits_W^T aliases qb_b..vT (dead after last attention)
    unsigned short* lw_t = (unsigned short*)(ws + 2097152);

    float* out_logits = out;                // 65,536,000
    float* out_mems   = out + 65536000;     // 33,554,432
    float* out_times  = out + 99090432;     // 8,192

    embed_kernel<<<BC * SEQC, 256, 0, stream>>>(tokens, token_emb, x);
    times_init_kernel<<<32, 256, 0, stream>>>(times, out_times, aux);

    for (int d = 0; d < 4; ++d) {
        const float* mem_d = mems + (size_t)d * BC * MC * DIMC;
        prep_kernel<<<PREP_TOT, 256, 0, stream>>>(
            mem_d, x, expire_W + d * DIMC, expire_b + d, exps, aux,
            mem_b, out_mems + (size_t)d * BC * MC * DIMC,
            ln1_g + d * DIMC, ln1_b + d * DIMC, xn_b,
            Wq + (size_t)d * DIMC * DIMC, Wkv + (size_t)d * DIMC * 2 * DIMC,
            Wo + (size_t)d * DIMC * DIMC, W1 + (size_t)d * DIMC * 4 * DIMC,
            W2 + (size_t)d * 4 * DIMC * DIMC,
            wq_t, wkv_t, wo_t, w1_t, w2_t);
        qkv_gemm_kernel<<<1408, 256, 0, stream>>>(xn_b, mem_b, wq_t, wkv_t, qb_b, kv_b);
        vt_kernel<<<dim3(40, 16, BC), 256, 0, stream>>>(kv_b, vT);
        attn_mfma_kernel<<<dim3(8, HEADSC, BC), 256, 0, stream>>>(
            qb_b, kv_b, vT, exps, times + d * MC, attn_b);
        gemm64_kernel<<<dim3(8, 32), 256, 0, stream>>>(
            attn_b, wo_t, bo + d * DIMC, x, x, nullptr, DIMC);
        ln_kernel<<<BC * SEQC, 256, 0, stream>>>(x, ln2_g + d * DIMC, ln2_b + d * DIMC, xn_b);
        ffn1_kernel<<<dim3(32, 16), 256, 0, stream>>>(xn_b, w1_t, b1 + d * 4 * DIMC, ffn_b);
        if (d < 3) {
            gemm64_kernel<<<dim3(8, 32), 256, 0, stream>>>(
                ffn_b, w2_t, b2 + d * DIMC, x, x, nullptr, 4 * DIMC);
        } else {
            gemm64_kernel<<<dim3(8, 32), 256, 0, stream>>>(
                ffn_b, w2_t, b2 + d * DIMC, x, nullptr, x_b, 4 * DIMC);
        }
    }

    wt_kernel<<<dim3(1000, 32), 256, 0, stream>>>(logits_W, lw_t, DIMC, VOCABC);
    logits_kernel<<<dim3(16, 250), 256, 0, stream>>>(x_b, lw_t, logits_b, out_logits);
    aux_write_kernel<<<1, 1, 0, stream>>>(aux, out + 99098624);
}

// Round 5
// 1795.852 us; speedup vs baseline: 5.4431x; 1.0481x over previous
//
#include <hip/hip_runtime.h>
#include <cmath>

// Problem constants
#define DIMC   1024
#define SEQC   512
#define BC     4
#define MC     2048      // MAXMEM
#define CTXC   2560      // MC + SEQC
#define HEADSC 16
#define DHC    64
#define VOCABC 32000

using short8 = __attribute__((ext_vector_type(8))) short;
using f32x4  = __attribute__((ext_vector_type(4))) float;
using u16x4  = __attribute__((ext_vector_type(4))) unsigned short;
using u16x8  = __attribute__((ext_vector_type(8))) unsigned short;

__device__ __forceinline__ unsigned short f2bf(float f) {
    unsigned u = __float_as_uint(f);
    unsigned r = (u + 0x7fffu + ((u >> 16) & 1u)) >> 16;
    return (unsigned short)r;
}

__device__ __forceinline__ void glds16(const unsigned short* g, char* l) {
    __builtin_amdgcn_global_load_lds(
        (const __attribute__((address_space(1))) void*)g,
        (__attribute__((address_space(3))) void*)l, 16, 0, 0);
}

// ---------------- embed ----------------
__global__ __launch_bounds__(256) void embed_kernel(const int* __restrict__ tokens,
                                                    const float* __restrict__ emb,
                                                    float* __restrict__ x) {
    int row = blockIdx.x;
    int tok = tokens[row];
    const float4 v = *(const float4*)(emb + (size_t)tok * DIMC + threadIdx.x * 4);
    *(float4*)(x + (size_t)row * DIMC + threadIdx.x * 4) = v;
}

// ---------------- new_times + aux zero ----------------
__global__ __launch_bounds__(256) void times_init_kernel(const int* __restrict__ times,
                                                         float* __restrict__ out_times,
                                                         float* __restrict__ aux) {
    int i = blockIdx.x * 256 + threadIdx.x;
    if (i == 0) aux[0] = 0.0f;
    if (i < 4 * MC) {
        int d = i >> 11, m = i & (MC - 1);
        out_times[i] = (m < MC - SEQC) ? (float)(times[d * MC + SEQC + m] + SEQC)
                                       : (float)(MC - 1 - m);
    }
}

// ---------------- fused per-layer prep ----------------
#define PREP_MEM 8192
#define PREP_XC  10240
#define PREP_LN  12288
#define PREP_TOT 24576
__global__ __launch_bounds__(256) void prep_kernel(
    const float* __restrict__ mem_d, const float* __restrict__ x,
    const float* __restrict__ eW, const float* __restrict__ eb,
    float* __restrict__ exps, float* __restrict__ aux,
    unsigned short* __restrict__ mem_b, float* __restrict__ out_mems_d,
    const float* __restrict__ g1, const float* __restrict__ b1v,
    unsigned short* __restrict__ xn_b,
    const float* __restrict__ Wq, const float* __restrict__ Wkv,
    const float* __restrict__ Wo, const float* __restrict__ W1,
    const float* __restrict__ W2,
    unsigned short* __restrict__ wq_t, unsigned short* __restrict__ wkv_t,
    unsigned short* __restrict__ wo_t, unsigned short* __restrict__ w1_t,
    unsigned short* __restrict__ w2_t) {
    __shared__ float sh[1056];
    const int bid = blockIdx.x, tid = threadIdx.x;
    if (bid < PREP_MEM) {
        int row = bid;                       // b*2048 + m
        int m = row & 2047, b = row >> 11;
        const float4 v = *(const float4*)(mem_d + (size_t)row * DIMC + tid * 4);
        const float4 w = *(const float4*)(eW + tid * 4);
        float s = v.x * w.x + v.y * w.y + v.z * w.z + v.w * w.w;
        for (int off = 32; off; off >>= 1) s += __shfl_down(s, off, 64);
        int wid = tid >> 6, lane = tid & 63;
        if (lane == 0) sh[wid] = s;
        u16x4 o = { f2bf(v.x), f2bf(v.y), f2bf(v.z), f2bf(v.w) };
        *(u16x4*)(mem_b + (size_t)row * DIMC + tid * 4) = o;
        if (m >= SEQC)
            *(float4*)(out_mems_d + ((size_t)(b * MC + m - SEQC)) * DIMC + tid * 4) = v;
        __syncthreads();
        if (tid == 0) {
            float z = sh[0] + sh[1] + sh[2] + sh[3] + eb[0];
            float e = (float)MC / (1.0f + expf(-z));
            exps[row] = e;
            atomicAdd(aux, e * (1e-6f / (float)SEQC));
        }
    } else if (bid < PREP_XC) {
        int r = bid - PREP_MEM;              // b*512 + i
        int b = r >> 9, i = r & 511;
        const float4 v = *(const float4*)(x + (size_t)r * DIMC + tid * 4);
        *(float4*)(out_mems_d + ((size_t)(b * MC + MC - SEQC + i)) * DIMC + tid * 4) = v;
    } else if (bid < PREP_LN) {
        int row = bid - PREP_XC;
        const float4 v = *(const float4*)(x + (size_t)row * DIMC + tid * 4);
        float s = v.x + v.y + v.z + v.w;
        float q = v.x * v.x + v.y * v.y + v.z * v.z + v.w * v.w;
        for (int off = 32; off; off >>= 1) {
            s += __shfl_down(s, off, 64);
            q += __shfl_down(q, off, 64);
        }
        int wid = tid >> 6, lane = tid & 63;
        if (lane == 0) { sh[wid] = s; sh[4 + wid] = q; }
        __syncthreads();
        if (tid == 0) {
            float S = sh[0] + sh[1] + sh[2] + sh[3];
            float Q = sh[4] + sh[5] + sh[6] + sh[7];
            float mu = S / DIMC;
            float var = Q / DIMC - mu * mu;
            sh[8] = mu;
            sh[9] = rsqrtf(var + 1e-5f);
        }
        __syncthreads();
        float mu = sh[8], rstd = sh[9];
        const float4 gg = *(const float4*)(g1 + tid * 4);
        const float4 bb = *(const float4*)(b1v + tid * 4);
        u16x4 o = { f2bf((v.x - mu) * rstd * gg.x + bb.x),
                    f2bf((v.y - mu) * rstd * gg.y + bb.y),
                    f2bf((v.z - mu) * rstd * gg.z + bb.z),
                    f2bf((v.w - mu) * rstd * gg.w + bb.w) };
        *(u16x4*)(xn_b + (size_t)row * DIMC + tid * 4) = o;
    } else {
        int t = bid - PREP_LN;
        const float* W; unsigned short* Wt; int K, N, tx, ty;
        if (t < 1024)      { W = Wq;  Wt = wq_t;  K = 1024; N = 1024; tx = t & 31;  ty = t >> 5; }
        else if (t < 3072) { int u = t - 1024; W = Wkv; Wt = wkv_t; K = 1024; N = 2048; tx = u & 63;  ty = u >> 6; }
        else if (t < 4096) { int u = t - 3072; W = Wo;  Wt = wo_t;  K = 1024; N = 1024; tx = u & 31;  ty = u >> 5; }
        else if (t < 8192) { int u = t - 4096; W = W1;  Wt = w1_t;  K = 1024; N = 4096; tx = u & 127; ty = u >> 7; }
        else               { int u = t - 8192; W = W2;  Wt = w2_t;  K = 4096; N = 1024; tx = u & 31;  ty = u >> 5; }
        int n0 = tx * 32, k0 = ty * 32;
        int r = tid >> 3, c = (tid & 7) * 4;
        const float4 v = *(const float4*)(W + (size_t)(k0 + r) * N + n0 + c);
        sh[r * 33 + c] = v.x; sh[r * 33 + c + 1] = v.y;
        sh[r * 33 + c + 2] = v.z; sh[r * 33 + c + 3] = v.w;
        __syncthreads();
        u16x4 o = { f2bf(sh[(c + 0) * 33 + r]), f2bf(sh[(c + 1) * 33 + r]),
                    f2bf(sh[(c + 2) * 33 + r]), f2bf(sh[(c + 3) * 33 + r]) };
        *(u16x4*)(Wt + (size_t)(n0 + r) * K + k0 + c) = o;
    }
}

// ---------------- compact live memory keys (deterministic ballot scan) ----------------
__global__ __launch_bounds__(64) void compact_kernel(
    const float* __restrict__ exps, const int* __restrict__ times_d,
    int* __restrict__ cidx, float* __restrict__ em_c, int* __restrict__ cnt) {
    int b = blockIdx.x, lane = threadIdx.x;
    int c = 0;
    for (int it = 0; it < 32; ++it) {
        int j = it * 64 + lane;
        float e = exps[b * MC + j];
        float rr = (e - (float)times_d[j]) * (1.0f / 128.0f) + 1.0f;
        float em = fminf(fmaxf(rr, 0.0f), 1.0f);
        unsigned long long mk = __ballot(em > 0.0f);
        int pos = c + __popcll(mk & ((1ull << lane) - 1ull));
        if (em > 0.0f) {
            cidx[b * 2048 + pos] = j;
            em_c[b * 2048 + pos] = em;
        }
        c += __popcll(mk);
    }
    int padded = (c + 63) & ~63;
    for (int p = c + lane; p < padded; p += 64) {
        cidx[b * 2048 + p] = 0;     // valid row; em=0 kills contribution
        em_c[b * 2048 + p] = 0.0f;
    }
    if (lane == 0) cnt[b] = padded >> 6;   // number of 64-wide compact tiles
}

// ---------------- LayerNorm (fp32 in, bf16 out) — LN2 ----------------
__global__ __launch_bounds__(256) void ln_kernel(const float* __restrict__ in,
                                                 const float* __restrict__ g,
                                                 const float* __restrict__ b,
                                                 unsigned short* __restrict__ outb) {
    int row = blockIdx.x;
    int tid = threadIdx.x;
    const float4 v = *(const float4*)(in + (size_t)row * DIMC + tid * 4);
    float s = v.x + v.y + v.z + v.w;
    float q = v.x * v.x + v.y * v.y + v.z * v.z + v.w * v.w;
    for (int off = 32; off; off >>= 1) {
        s += __shfl_down(s, off, 64);
        q += __shfl_down(q, off, 64);
    }
    __shared__ float ss[4], sq[4];
    int wid = tid >> 6, lane = tid & 63;
    if (lane == 0) { ss[wid] = s; sq[wid] = q; }
    __syncthreads();
    if (tid == 0) {
        float S = ss[0] + ss[1] + ss[2] + ss[3];
        float Q = sq[0] + sq[1] + sq[2] + sq[3];
        float mu = S / DIMC;
        float var = Q / DIMC - mu * mu;
        ss[0] = mu;
        sq[0] = rsqrtf(var + 1e-5f);
    }
    __syncthreads();
    float mu = ss[0], rstd = sq[0];
    const float4 gg = *(const float4*)(g + tid * 4);
    const float4 bb = *(const float4*)(b + tid * 4);
    u16x4 o = { f2bf((v.x - mu) * rstd * gg.x + bb.x),
                f2bf((v.y - mu) * rstd * gg.y + bb.y),
                f2bf((v.z - mu) * rstd * gg.z + bb.z),
                f2bf((v.w - mu) * rstd * gg.w + bb.w) };
    *(u16x4*)(outb + (size_t)row * DIMC + tid * 4) = o;
}

// ---------------- weight convert + transpose (logits_W only) ----------------
__global__ __launch_bounds__(256) void wt_kernel(const float* __restrict__ W,
                                                 unsigned short* __restrict__ Wt,
                                                 int K, int N) {
    __shared__ float t[32][33];
    int tid = threadIdx.x;
    int n0 = blockIdx.x * 32, k0 = blockIdx.y * 32;
    int r = tid >> 3, c = (tid & 7) * 4;
    const float4 v = *(const float4*)(W + (size_t)(k0 + r) * N + n0 + c);
    t[r][c] = v.x; t[r][c + 1] = v.y; t[r][c + 2] = v.z; t[r][c + 3] = v.w;
    __syncthreads();
    u16x4 o = { f2bf(t[c + 0][r]), f2bf(t[c + 1][r]),
                f2bf(t[c + 2][r]), f2bf(t[c + 3][r]) };
    *(u16x4*)(Wt + (size_t)(n0 + r) * K + k0 + c) = o;
}

// ---------------- local V transpose: j in [2048,2560) ----------------
__global__ __launch_bounds__(256) void vt_kernel(const unsigned short* __restrict__ kvb,
                                                 unsigned short* __restrict__ vT) {
    __shared__ unsigned short t[64][72];
    int jt = blockIdx.x, dt = blockIdx.y, b = blockIdx.z;
    int j0 = MC + jt * 64;
    int tid = threadIdx.x;
    int r = tid >> 3, c = (tid & 7) * 8;
    #pragma unroll
    for (int p = 0; p < 2; ++p) {
        u16x8 v = *(const u16x8*)(kvb + ((size_t)(b * CTXC + j0 + r + p * 32)) * 2048
                                  + 1024 + dt * 64 + c);
        *(u16x8*)&t[r + p * 32][c] = v;
    }
    __syncthreads();
    #pragma unroll
    for (int p = 0; p < 2; ++p) {
        int dr = r + p * 32;
        u16x8 o = { t[c + 0][dr], t[c + 1][dr], t[c + 2][dr], t[c + 3][dr],
                    t[c + 4][dr], t[c + 5][dr], t[c + 6][dr], t[c + 7][dr] };
        *(u16x8*)(vT + ((size_t)(b * 1024 + dt * 64 + dr)) * CTXC + j0 + c) = o;
    }
}

// ---------------- compact V gather-transpose: vTc[b][d][slot] ----------------
__global__ __launch_bounds__(256) void vtc_kernel(const unsigned short* __restrict__ kvb,
                                                  const int* __restrict__ cidx,
                                                  const int* __restrict__ cnt,
                                                  unsigned short* __restrict__ vTc) {
    int ct = blockIdx.x, dt = blockIdx.y, b = blockIdx.z;
    if (ct >= cnt[b]) return;
    __shared__ unsigned short t[64][72];
    int tid = threadIdx.x;
    int r = tid >> 3, c = (tid & 7) * 8;
    #pragma unroll
    for (int p = 0; p < 2; ++p) {
        int row = cidx[b * 2048 + ct * 64 + r + p * 32];
        u16x8 v = *(const u16x8*)(kvb + ((size_t)(b * CTXC + row)) * 2048
                                  + 1024 + dt * 64 + c);
        *(u16x8*)&t[r + p * 32][c] = v;
    }
    __syncthreads();
    #pragma unroll
    for (int p = 0; p < 2; ++p) {
        int dr = r + p * 32;
        u16x8 o = { t[c + 0][dr], t[c + 1][dr], t[c + 2][dr], t[c + 3][dr],
                    t[c + 4][dr], t[c + 5][dr], t[c + 6][dr], t[c + 7][dr] };
        *(u16x8*)(vTc + ((size_t)(b * 1024 + dt * 64 + dr)) * 2048 + ct * 64 + c) = o;
    }
}

// ---------------- bf16 MFMA GEMM body (m97 structure, RT = 128 or 64) ----------------
template<bool GATHER, bool BIAS, bool GELU, bool RES, int RT>
__device__ __forceinline__ void gemm_body(
    unsigned short* As, unsigned short* Bs,
    const unsigned short* __restrict__ A, const unsigned short* __restrict__ A2,
    const unsigned short* __restrict__ Wt, const float* __restrict__ bias,
    const float* __restrict__ res, float* __restrict__ Cf,
    unsigned short* __restrict__ Cb, int K, int N, int bx, int by) {
    constexpr int MF = RT / 32;
    const int tid = threadIdx.x;
    const int lane = tid & 63, wave = tid >> 6;
    const int row0 = by * RT, col0 = bx * 128;

    const int seg = tid & 3;
    const int rr0 = tid >> 2;
    const unsigned short* arow[RT / 64];
    #pragma unroll
    for (int p = 0; p < RT / 64; ++p) {
        int r = row0 + p * 64 + rr0;
        if (GATHER) {
            int b = r / CTXC, rm = r - b * CTXC;
            arow[p] = (rm < MC) ? A + ((size_t)(b * MC + rm)) * K
                                : A2 + ((size_t)(b * SEQC + rm - MC)) * K;
        } else {
            arow[p] = A + (size_t)r * K;
        }
        arow[p] += seg * 8;
    }
    const unsigned short* brow[2];
    #pragma unroll
    for (int p = 0; p < 2; ++p)
        brow[p] = Wt + (size_t)(col0 + p * 64 + rr0) * K + seg * 8;

    char* lA0 = (char*)As + (size_t)(tid & 192) * 16;
    char* lB0 = (char*)Bs + (size_t)(tid & 192) * 16;
    char* lB1 = lB0 + 4096;

    f32x4 acc[MF][4] = {};

    const int wr = (wave >> 1) * (RT / 2), wc = (wave & 1) * 64;
    const int fr = lane & 15;
    const int k8 = (lane >> 4) * 8;
    const unsigned short* Ar = As + (size_t)(wr + fr) * 32 + k8;
    const unsigned short* Br = Bs + (size_t)(wc + fr) * 32 + k8;

    for (int k0 = 0; k0 < K; k0 += 32) {
        glds16(arow[0] + k0, lA0);
        if (RT == 128) glds16(arow[1] + k0, lA0 + 4096);
        glds16(brow[0] + k0, lB0);
        glds16(brow[1] + k0, lB1);
        __syncthreads();
        short8 a[MF], b[4];
        #pragma unroll
        for (int m = 0; m < MF; ++m) a[m] = *(const short8*)(Ar + m * 16 * 32);
        #pragma unroll
        for (int n = 0; n < 4; ++n) b[n] = *(const short8*)(Br + n * 16 * 32);
        #pragma unroll
        for (int m = 0; m < MF; ++m)
            #pragma unroll
            for (int n = 0; n < 4; ++n)
                acc[m][n] = __builtin_amdgcn_mfma_f32_16x16x32_bf16(a[m], b[n], acc[m][n], 0, 0, 0);
        __syncthreads();
    }

    const int orow = row0 + wr + (lane >> 4) * 4;
    const int ocol = col0 + wc + fr;
    #pragma unroll
    for (int n = 0; n < 4; ++n) {
        int c = ocol + n * 16;
        float bv = BIAS ? bias[c] : 0.0f;
        #pragma unroll
        for (int m = 0; m < MF; ++m) {
            #pragma unroll
            for (int i = 0; i < 4; ++i) {
                size_t idx = (size_t)(orow + m * 16 + i) * N + c;
                float v = acc[m][n][i] + bv;
                if (GELU) v = 0.5f * v * (1.0f + erff(v * 0.70710678118f));
                if (RES) v += res[idx];
                if (Cf) Cf[idx] = v;
                if (Cb) Cb[idx] = f2bf(v);
            }
        }
    }
}

// Q (128 blocks) + KV (1280 blocks) fused dispatch
__global__ __launch_bounds__(256) void qkv_gemm_kernel(
    const unsigned short* __restrict__ xn_b, const unsigned short* __restrict__ mem_b,
    const unsigned short* __restrict__ wq_t, const unsigned short* __restrict__ wkv_t,
    unsigned short* __restrict__ qb, unsigned short* __restrict__ kvb) {
    __shared__ unsigned short As[128 * 32];
    __shared__ unsigned short Bs[128 * 32];
    int id = blockIdx.x;
    if (id < 128) {
        gemm_body<false, false, false, false, 128>(As, Bs, xn_b, nullptr, wq_t,
            nullptr, nullptr, nullptr, qb, 1024, 1024, id & 7, id >> 3);
    } else {
        id -= 128;
        gemm_body<true, false, false, false, 128>(As, Bs, mem_b, xn_b, wkv_t,
            nullptr, nullptr, nullptr, kvb, 1024, 2048, id & 15, id >> 4);
    }
}

// RT=64 GEMM with bias+residual, N=1024 (Wo and FFN2)
__global__ __launch_bounds__(256) void gemm64_kernel(
    const unsigned short* __restrict__ A, const unsigned short* __restrict__ Wt,
    const float* __restrict__ bias, const float* __restrict__ res,
    float* __restrict__ Cf, unsigned short* __restrict__ Cb, int K) {
    __shared__ unsigned short As[64 * 32];
    __shared__ unsigned short Bs[128 * 32];
    gemm_body<false, true, false, true, 64>(As, Bs, A, nullptr, Wt, bias, res,
        Cf, Cb, K, 1024, blockIdx.x, blockIdx.y);
}

// FFN1: gelu, bf16 out
__global__ __launch_bounds__(256) void ffn1_kernel(
    const unsigned short* __restrict__ A, const unsigned short* __restrict__ Wt,
    const float* __restrict__ bias, unsigned short* __restrict__ Cb) {
    __shared__ unsigned short As[128 * 32];
    __shared__ unsigned short Bs[128 * 32];
    gemm_body<false, true, true, false, 128>(As, Bs, A, nullptr, Wt, bias, nullptr,
        nullptr, Cb, 1024, 4096, blockIdx.x, blockIdx.y);
}

// logits: grid (16 rows, 250 cols) — row-tiles fastest for B-tile L2 reuse
__global__ __launch_bounds__(256) void logits_kernel(
    const unsigned short* __restrict__ A, const unsigned short* __restrict__ Wt,
    const float* __restrict__ bias, float* __restrict__ Cf) {
    __shared__ unsigned short As[128 * 32];
    __shared__ unsigned short Bs[128 * 32];
    gemm_body<false, true, false, false, 128>(As, Bs, A, nullptr, Wt, bias, nullptr,
        Cf, nullptr, 1024, VOCABC, blockIdx.y, blockIdx.x);
}

// ---------------- 3-phase MFMA flash attention with expire mask ----------------
// Swapped QK^T (mfma(K,Q)): key axis lane-local -> 4 shfl per tile reduction.
// Phase1: 32 mem tiles, QK + m/l only (em==0 for V there except compact set).
// Phase2: qt+1 local tiles, full flash (em==1).
// Phase3: compact live-mem tiles, P=exp(s-m_fin)*em, PV only.
__global__ __launch_bounds__(256) void attn_mfma_kernel(
    const unsigned short* __restrict__ qb,
    const unsigned short* __restrict__ kvb,
    const unsigned short* __restrict__ vT,
    const unsigned short* __restrict__ vTc,
    const int* __restrict__ cidx,
    const float* __restrict__ em_c,
    const int* __restrict__ cnt,
    unsigned short* __restrict__ outb) {
    __shared__ unsigned short K_s[64 * 64];
    __shared__ unsigned short V_s[64 * 64];
    __shared__ unsigned short p_s[4][16][72];
    __shared__ float em_s[64];
    const int tid = threadIdx.x;
    const int lane = tid & 63, wave = tid >> 6;
    const int qt = blockIdx.x, h = blockIdx.y, b = blockIdx.z;
    const int fr = lane & 15, g = lane >> 4;
    const int gq = qt * 64 + wave * 16;

    short8 aq[2];
    {
        const unsigned short* qp = qb + ((size_t)(b * SEQC + gq + fr)) * DIMC + h * DHC + g * 8;
        aq[0] = *(const short8*)qp;
        aq[1] = *(const short8*)(qp + 32);
    }

    const int sr = tid >> 3, ss = tid & 7;
    char* ldk = (char*)K_s + (tid & 192) * 16;
    char* ldv = (char*)V_s + (tid & 192) * 16;

    f32x4 acc_o[4] = {};
    float m_q = -1e30f, l_q = 0.0f;

    // ---- phase 1: memory tiles, denominator only ----
    for (int kt = 0; kt < 32; ++kt) {
        const int jbase = kt * 64;
        __syncthreads();
        #pragma unroll
        for (int p = 0; p < 2; ++p) {
            int r = sr + p * 32, sw = (ss ^ (r & 7)) * 8;
            glds16(kvb + ((size_t)(b * CTXC + jbase + r)) * 2048 + h * DHC + sw, ldk + p * 4096);
        }
        __syncthreads();
        f32x4 sT[4] = {};
        #pragma unroll
        for (int ks = 0; ks < 2; ++ks)
            #pragma unroll
            for (int mf = 0; mf < 4; ++mf) {
                int row = mf * 16 + fr, sg = (ks * 4 + g) ^ (row & 7);
                short8 kk = *(const short8*)((const char*)K_s + row * 128 + sg * 16);
                sT[mf] = __builtin_amdgcn_mfma_f32_16x16x32_bf16(kk, aq[ks], sT[mf], 0, 0, 0);
            }
        float mx = sT[0][0];
        #pragma unroll
        for (int mf = 0; mf < 4; ++mf)
            #pragma unroll
            for (int i = 0; i < 4; ++i) mx = fmaxf(mx, sT[mf][i]);
        mx *= 0.125f;
        mx = fmaxf(mx, __shfl_xor(mx, 16, 64));
        mx = fmaxf(mx, __shfl_xor(mx, 32, 64));
        float mnew = fmaxf(m_q, mx);
        float fs = __expf(m_q - mnew);
        m_q = mnew;
        float ps = 0.0f;
        #pragma unroll
        for (int mf = 0; mf < 4; ++mf)
            #pragma unroll
            for (int i = 0; i < 4; ++i)
                ps += __expf(sT[mf][i] * 0.125f - mnew);
        ps += __shfl_xor(ps, 16, 64);
        ps += __shfl_xor(ps, 32, 64);
        l_q = l_q * fs + ps;
    }

    // ---- phase 2: local tiles, full flash (em == 1) ----
    const int nlt = qt + 1;
    for (int lt = 0; lt < nlt; ++lt) {
        const int jbase = MC + lt * 64;
        __syncthreads();
        #pragma unroll
        for (int p = 0; p < 2; ++p) {
            int r = sr + p * 32, sw = (ss ^ (r & 7)) * 8;
            glds16(kvb + ((size_t)(b * CTXC + jbase + r)) * 2048 + h * DHC + sw, ldk + p * 4096);
            glds16(vT + ((size_t)(b * 1024 + h * DHC + r)) * CTXC + jbase + sw, ldv + p * 4096);
        }
        __syncthreads();
        f32x4 sT[4] = {};
        #pragma unroll
        for (int ks = 0; ks < 2; ++ks)
            #pragma unroll
            for (int mf = 0; mf < 4; ++mf) {
                int row = mf * 16 + fr, sg = (ks * 4 + g) ^ (row & 7);
                short8 kk = *(const short8*)((const char*)K_s + row * 128 + sg * 16);
                sT[mf] = __builtin_amdgcn_mfma_f32_16x16x32_bf16(kk, aq[ks], sT[mf], 0, 0, 0);
            }
        const int kq = gq + fr - lt * 64;   // max allowed local key index
        float sv[4][4];
        #pragma unroll
        for (int mf = 0; mf < 4; ++mf)
            #pragma unroll
            for (int i = 0; i < 4; ++i) {
                int kl = mf * 16 + g * 4 + i;
                sv[mf][i] = (kl <= kq) ? sT[mf][i] * 0.125f : -1e30f;
            }
        float mx = sv[0][0];
        #pragma unroll
        for (int mf = 0; mf < 4; ++mf)
            #pragma unroll
            for (int i = 0; i < 4; ++i) mx = fmaxf(mx, sv[mf][i]);
        mx = fmaxf(mx, __shfl_xor(mx, 16, 64));
        mx = fmaxf(mx, __shfl_xor(mx, 32, 64));
        float mnew = fmaxf(m_q, mx);
        float fs = __expf(m_q - mnew);
        m_q = mnew;
        float ps = 0.0f;
        #pragma unroll
        for (int mf = 0; mf < 4; ++mf)
            #pragma unroll
            for (int i = 0; i < 4; ++i) {
                float pe = __expf(sv[mf][i] - mnew);
                ps += pe;
                p_s[wave][fr][mf * 16 + g * 4 + i] = f2bf(pe);
            }
        ps += __shfl_xor(ps, 16, 64);
        ps += __shfl_xor(ps, 32, 64);
        l_q = l_q * fs + ps;
        float fsr[4];
        #pragma unroll
        for (int i = 0; i < 4; ++i) fsr[i] = __shfl(fs, g * 4 + i, 64);
        #pragma unroll
        for (int n = 0; n < 4; ++n)
            #pragma unroll
            for (int i = 0; i < 4; ++i) acc_o[n][i] *= fsr[i];
        asm volatile("s_waitcnt lgkmcnt(0)" ::: "memory");
        #pragma unroll
        for (int ks = 0; ks < 2; ++ks) {
            short8 ap = *(const short8*)&p_s[wave][fr][ks * 32 + g * 8];
            #pragma unroll
            for (int n = 0; n < 4; ++n) {
                int row = n * 16 + fr, sg = (ks * 4 + g) ^ (row & 7);
                short8 bv = *(const short8*)((const char*)V_s + row * 128 + sg * 16);
                acc_o[n] = __builtin_amdgcn_mfma_f32_16x16x32_bf16(ap, bv, acc_o[n], 0, 0, 0);
            }
        }
    }

    // ---- phase 3: compact live-mem tiles (final m,l; no m/l update) ----
    const int nct = cnt[b];
    for (int ct = 0; ct < nct; ++ct) {
        __syncthreads();
        #pragma unroll
        for (int p = 0; p < 2; ++p) {
            int r = sr + p * 32, sw = (ss ^ (r & 7)) * 8;
            int row = cidx[b * 2048 + ct * 64 + r];
            glds16(kvb + ((size_t)(b * CTXC + row)) * 2048 + h * DHC + sw, ldk + p * 4096);
            glds16(vTc + ((size_t)(b * 1024 + h * DHC + r)) * 2048 + ct * 64 + sw, ldv + p * 4096);
        }
        if (tid < 64) em_s[tid] = em_c[b * 2048 + ct * 64 + tid];
        __syncthreads();
        f32x4 sT[4] = {};
        #pragma unroll
        for (int ks = 0; ks < 2; ++ks)
            #pragma unroll
            for (int mf = 0; mf < 4; ++mf) {
                int row = mf * 16 + fr, sg = (ks * 4 + g) ^ (row & 7);
                short8 kk = *(const short8*)((const char*)K_s + row * 128 + sg * 16);
                sT[mf] = __builtin_amdgcn_mfma_f32_16x16x32_bf16(kk, aq[ks], sT[mf], 0, 0, 0);
            }
        #pragma unroll
        for (int mf = 0; mf < 4; ++mf)
            #pragma unroll
            for (int i = 0; i < 4; ++i) {
                int key = mf * 16 + g * 4 + i;
                float pe = __expf(sT[mf][i] * 0.125f - m_q) * em_s[key];
                p_s[wave][fr][key] = f2bf(pe);
            }
        asm volatile("s_waitcnt lgkmcnt(0)" ::: "memory");
        #pragma unroll
        for (int ks = 0; ks < 2; ++ks) {
            short8 ap = *(const short8*)&p_s[wave][fr][ks * 32 + g * 8];
            #pragma unroll
            for (int n = 0; n < 4; ++n) {
                int row = n * 16 + fr, sg = (ks * 4 + g) ^ (row & 7);
                short8 bv = *(const short8*)((const char*)V_s + row * 128 + sg * 16);
                acc_o[n] = __builtin_amdgcn_mfma_f32_16x16x32_bf16(ap, bv, acc_o[n], 0, 0, 0);
            }
        }
    }

    float linv = 1.0f / l_q;
    float invr[4];
    #pragma unroll
    for (int i = 0; i < 4; ++i) invr[i] = __shfl(linv, g * 4 + i, 64);
    #pragma unroll
    for (int n = 0; n < 4; ++n) {
        #pragma unroll
        for (int i = 0; i < 4; ++i) {
            size_t idx = ((size_t)(b * SEQC + gq + g * 4 + i)) * DIMC + h * DHC + n * 16 + fr;
            outb[idx] = f2bf(acc_o[n][i] * invr[i]);
        }
    }
}

// ---------------- aux writeback ----------------
__global__ void aux_write_kernel(const float* __restrict__ aux, float* __restrict__ dst) {
    dst[0] = aux[0];
}

extern "C" void kernel_launch(void* const* d_in, const int* in_sizes, int n_in,
                              void* d_out, int out_size, void* d_ws, size_t ws_size,
                              hipStream_t stream) {
    const int*   tokens    = (const int*)d_in[0];
    const float* mems      = (const float*)d_in[1];
    const int*   times     = (const int*)d_in[2];
    const float* token_emb = (const float*)d_in[3];
    const float* expire_W  = (const float*)d_in[4];
    const float* expire_b  = (const float*)d_in[5];
    const float* ln1_g     = (const float*)d_in[6];
    const float* ln1_b     = (const float*)d_in[7];
    const float* Wq        = (const float*)d_in[8];
    const float* Wkv       = (const float*)d_in[9];
    const float* Wo        = (const float*)d_in[10];
    const float* bo        = (const float*)d_in[11];
    const float* ln2_g     = (const float*)d_in[12];
    const float* ln2_b     = (const float*)d_in[13];
    const float* W1        = (const float*)d_in[14];
    const float* b1        = (const float*)d_in[15];
    const float* W2        = (const float*)d_in[16];
    const float* b2        = (const float*)d_in[17];
    const float* logits_W  = (const float*)d_in[18];
    const float* logits_b  = (const float*)d_in[19];

    float* out = (float*)d_out;
    float* ws  = (float*)d_ws;

    // workspace layout (float slots)
    float* x = ws;                                                 // 2,097,152
    unsigned short* qb_b  = (unsigned short*)(ws + 2097152);       // 2,097,152 u16
    unsigned short* kv_b  = (unsigned short*)(ws + 3145728);       // 20,971,520 u16
    unsigned short* vT    = (unsigned short*)(ws + 13631488);      // 10,485,760 u16
    unsigned short* xn_b  = (unsigned short*)(ws + 18874368);      // 2,097,152 u16
    unsigned short* attn_b= (unsigned short*)(ws + 19922944);      // 2,097,152 u16
    unsigned short* ffn_b = (unsigned short*)(ws + 20971520);      // 8,388,608 u16
    unsigned short* mem_b = (unsigned short*)(ws + 25165824);      // 8,388,608 u16
    unsigned short* x_b   = (unsigned short*)(ws + 29360128);      // 2,097,152 u16
    unsigned short* wq_t  = (unsigned short*)(ws + 30408704);      // 1,048,576 u16
    unsigned short* wkv_t = (unsigned short*)(ws + 30932992);      // 2,097,152 u16
    unsigned short* wo_t  = (unsigned short*)(ws + 31981568);      // 1,048,576 u16
    unsigned short* w1_t  = (unsigned short*)(ws + 32505856);      // 4,194,304 u16
    unsigned short* w2_t  = (unsigned short*)(ws + 34603008);      // 4,194,304 u16
    float* exps = ws + 36700160;                                   // 8,192
    float* aux  = ws + 36708352;                                   // 16
    unsigned short* vTc = (unsigned short*)(ws + 36708368);        // 8,388,608 u16 (4,194,304 f)
    int*   cidx = (int*)(ws + 40902672);                           // 8,192
    float* em_c = ws + 40910864;                                   // 8,192
    int*   cnt  = (int*)(ws + 40919056);                           // 4
    // logits_W^T aliases qb_b..vT (dead after last attention)
    unsigned short* lw_t = (unsigned short*)(ws + 2097152);

    float* out_logits = out;                // 65,536,000
    float* out_mems   = out + 65536000;     // 33,554,432
    float* out_times  = out + 99090432;     // 8,192

    embed_kernel<<<BC * SEQC, 256, 0, stream>>>(tokens, token_emb, x);
    times_init_kernel<<<32, 256, 0, stream>>>(times, out_times, aux);

    for (int d = 0; d < 4; ++d) {
        const float* mem_d = mems + (size_t)d * BC * MC * DIMC;
        prep_kernel<<<PREP_TOT, 256, 0, stream>>>(
            mem_d, x, expire_W + d * DIMC, expire_b + d, exps, aux,
            mem_b, out_mems + (size_t)d * BC * MC * DIMC,
            ln1_g + d * DIMC, ln1_b + d * DIMC, xn_b,
            Wq + (size_t)d * DIMC * DIMC, Wkv + (size_t)d * DIMC * 2 * DIMC,
            Wo + (size_t)d * DIMC * DIMC, W1 + (size_t)d * DIMC * 4 * DIMC,
            W2 + (size_t)d * 4 * DIMC * DIMC,
            wq_t, wkv_t, wo_t, w1_t, w2_t);
        compact_kernel<<<BC, 64, 0, stream>>>(exps, times + d * MC, cidx, em_c, cnt);
        qkv_gemm_kernel<<<1408, 256, 0, stream>>>(xn_b, mem_b, wq_t, wkv_t, qb_b, kv_b);
        vt_kernel<<<dim3(8, 16, BC), 256, 0, stream>>>(kv_b, vT);
        vtc_kernel<<<dim3(32, 16, BC), 256, 0, stream>>>(kv_b, cidx, cnt, vTc);
        attn_mfma_kernel<<<dim3(8, HEADSC, BC), 256, 0, stream>>>(
            qb_b, kv_b, vT, vTc, cidx, em_c, cnt, attn_b);
        gemm64_kernel<<<dim3(8, 32), 256, 0, stream>>>(
            attn_b, wo_t, bo + d * DIMC, x, x, nullptr, DIMC);
        ln_kernel<<<BC * SEQC, 256, 0, stream>>>(x, ln2_g + d * DIMC, ln2_b + d * DIMC, xn_b);
        ffn1_kernel<<<dim3(32, 16), 256, 0, stream>>>(xn_b, w1_t, b1 + d * 4 * DIMC, ffn_b);
        if (d < 3) {
            gemm64_kernel<<<dim3(8, 32), 256, 0, stream>>>(
                ffn_b, w2_t, b2 + d * DIMC, x, x, nullptr, 4 * DIMC);
        } else {
            gemm64_kernel<<<dim3(8, 32), 256, 0, stream>>>(
                ffn_b, w2_t, b2 + d * DIMC, x, nullptr, x_b, 4 * DIMC);
        }
    }

    wt_kernel<<<dim3(1000, 32), 256, 0, stream>>>(logits_W, lw_t, DIMC, VOCABC);
    logits_kernel<<<dim3(16, 250), 256, 0, stream>>>(x_b, lw_t, logits_b, out_logits);
    aux_write_kernel<<<1, 1, 0, stream>>>(aux, out + 99098624);
}